// Round 3
// baseline (5024.972 us; speedup 1.0000x reference)
//
#include <hip/hip_runtime.h>
#include <math.h>

#define HILB  4096
#define FEAT  256
#define OUTW  4098          // 4096 probs + entropy + entangle
#define GSTR  65            // planar G row stride (fallback kernel)
#define G2STR 66            // float2 G row stride in eig kernel: bank=(4i+2j)%32, <=2-way

__device__ __forceinline__ float sanout(float v) {
    return (v == v && fabsf(v) < 1e30f) ? v : 1e6f;  // readable failure signature
}

// ===================== kernel 1: front (h, gates, amps, probs, entropy, G -> ws) ==========
__launch_bounds__(256, 8)
__global__ void qsp_front(const float* __restrict__ X,  const float* __restrict__ W1,
                          const float* __restrict__ B1, const float* __restrict__ W2,
                          const float* __restrict__ B2, const float* __restrict__ EP,
                          float* __restrict__ out, float2* __restrict__ G)
{
    __shared__ float2 vc2[8][64];          // 8 rows of M staging
    __shared__ float  sx[FEAT];
    __shared__ float  sh[48];
    __shared__ float  T8[8];
    __shared__ float  red[4];
    __shared__ float  s_inv2;

    const int tid  = threadIdx.x;
    const int b    = blockIdx.x;
    const int lane = tid & 63;
    const int wv   = tid >> 6;

    sx[tid] = X[b * FEAT + tid];
    __syncthreads();
    if (tid < 48) {
        float acc = B1[tid];
        for (int t = 0; t < FEAT; ++t) acc += sx[t] * W1[t * 48 + tid];
        sh[tid] = tanhf(acc);
    }
    if (tid == 64) {   // gate product on one thread of wave 1 (overlaps with h)
        float t00r=1.f,t00i=0.f,t01r=0.f,t01i=0.f,t10r=0.f,t10i=0.f,t11r=1.f,t11i=0.f;
        for (int g = 0; g < 33; ++g) {
            int d = g / 11, q = g % 11;
            const float* p = EP + (d * 12 + q) * 4;
            float th = p[0], ph = p[1], la = p[2], ga = p[3];
            float c  = cosf(0.5f * th), sn = sinf(0.5f * th);
            float ephr = cosf(ph), ephi = sinf(ph);
            float elar = cosf(la), elai = sinf(la);
            float egar = cosf(ga), egai = sinf(ga);
            float r00r =  c,          r00i = 0.f;
            float r01r = -elar * sn,  r01i = -elai * sn;
            float r10r =  ephr * sn,  r10i =  ephi * sn;
            float r11r =  egar * c,   r11i =  egai * c;
            float n00r = t00r*r00r - t00i*r00i + t01r*r10r - t01i*r10i;
            float n00i = t00r*r00i + t00i*r00r + t01r*r10i + t01i*r10r;
            float n01r = t00r*r01r - t00i*r01i + t01r*r11r - t01i*r11i;
            float n01i = t00r*r01i + t00i*r01r + t01r*r11i + t01i*r11r;
            float n10r = t10r*r00r - t10i*r00i + t11r*r10r - t11i*r10i;
            float n10i = t10r*r00i + t10i*r00r + t11r*r10i + t11i*r10r;
            float n11r = t10r*r01r - t10i*r01i + t11r*r11r - t11i*r11i;
            float n11i = t10r*r01i + t10i*r01r + t11r*r11i + t11i*r11r;
            t00r=n00r; t00i=n00i; t01r=n01r; t01i=n01i;
            t10r=n10r; t10i=n10i; t11r=n11r; t11i=n11i;
        }
        T8[0]=t00r; T8[1]=t00i; T8[2]=t01r; T8[3]=t01i;
        T8[4]=t10r; T8[5]=t10i; T8[6]=t11r; T8[7]=t11i;
    }
    __syncthreads();

    float accRe[16], accIm[16];
    #pragma unroll
    for (int jj = 0; jj < 16; ++jj) { accRe[jj] = 0.f; accIm[jj] = 0.f; }
    float ssq = 0.f;

    const int part = (tid >> 4) & 1;
    const int lr   = tid >> 5;
    const int c0   = (tid & 15) * 4;

    for (int it = 0; it < 8; ++it) {
        int row = it * 8 + lr;
        int j0  = part * HILB + row * 64 + c0;
        float a0 = B2[j0], a1 = B2[j0+1], a2 = B2[j0+2], a3 = B2[j0+3];
        for (int k = 0; k < 48; ++k) {
            float4 w4 = *(const float4*)(W2 + k * 8192 + j0);
            float hk = sh[k];
            a0 += hk * w4.x; a1 += hk * w4.y;
            a2 += hk * w4.z; a3 += hk * w4.w;
        }
        float* vf = (float*)&vc2[lr][0];
        vf[(c0+0)*2 + part] = a0;
        vf[(c0+1)*2 + part] = a1;
        vf[(c0+2)*2 + part] = a2;
        vf[(c0+3)*2 + part] = a3;
        __syncthreads();

        if (it == 0) {                     // apply gate product T to raw psi0, psi1
            if (tid == 0) {
                float2 s0 = vc2[0][0], s1 = vc2[0][1];
                float n0r = s0.x*T8[0] - s0.y*T8[1] + s1.x*T8[4] - s1.y*T8[5];
                float n0i = s0.x*T8[1] + s0.y*T8[0] + s1.x*T8[5] + s1.y*T8[4];
                float n1r = s0.x*T8[2] - s0.y*T8[3] + s1.x*T8[6] - s1.y*T8[7];
                float n1i = s0.x*T8[3] + s0.y*T8[2] + s1.x*T8[7] + s1.y*T8[6];
                vc2[0][0] = make_float2(n0r, n0i);
                vc2[0][1] = make_float2(n1r, n1i);
            }
            __syncthreads();
        }

        #pragma unroll
        for (int s = 0; s < 2; ++s) {      // raw probs out; rescaled after norm
            int jo  = tid + s * 256;
            int lr2 = jo >> 6, cc = jo & 63;
            float2 v = vc2[lr2][cc];
            float praw = v.x * v.x + v.y * v.y;
            out[(size_t)b * OUTW + it * 512 + jo] = praw;
            ssq += praw;
        }

        for (int rr = 0; rr < 8; ++rr) {   // raw Gram accumulation
            float2 vq = vc2[rr][lane];
            #pragma unroll
            for (int jj = 0; jj < 16; ++jj) {
                float2 vp = vc2[rr][wv * 16 + jj];
                accRe[jj] += vp.x * vq.x + vp.y * vq.y;
                accIm[jj] += vp.x * vq.y - vp.y * vq.x;
            }
        }
        __syncthreads();
    }

    // norm -> inv2, entropy
    {
        float v = ssq;
        #pragma unroll
        for (int off = 32; off; off >>= 1) v += __shfl_down(v, off, 64);
        if (lane == 0) red[wv] = v;
        __syncthreads();
        if (tid == 0) {
            float tot = red[0] + red[1] + red[2] + red[3];
            float nrm = sqrtf(tot);
            float inv = 1.f / fmaxf(nrm, 1e-12f);
            float i2  = inv * inv;
            s_inv2 = i2;
            float n2  = tot * i2;
            float lam = fmaxf(n2, 1e-12f);
            out[(size_t)b * OUTW + HILB] = sanout(-lam * logf(lam) + 1.1314877e-7f);
        }
        __syncthreads();
    }
    const float inv2 = s_inv2;

    // scaled G straight from registers to workspace (coalesced float2)
    float2* gb = G + (size_t)b * 4096;
    #pragma unroll
    for (int jj = 0; jj < 16; ++jj) {
        int p = wv * 16 + jj;
        gb[p * 64 + lane] = make_float2(inv2 * accRe[jj], inv2 * accIm[jj]);
    }

    // rescale own prob slots (same-thread RAW)
    #pragma unroll
    for (int i = 0; i < 16; ++i) {
        size_t idx = (size_t)b * OUTW + (i >> 1) * 512 + (i & 1) * 256 + tid;
        out[idx] = sanout(inv2 * out[idx]);
    }
}

// ===================== kernel 2: eigensolve (2 barriers/step, 4-wave parallel) ============
__launch_bounds__(256, 4)
__global__ void eig_kernel(const float2* __restrict__ G, float* __restrict__ out)
{
    __shared__ float2 GC[64 * G2STR];      // 33792 B, stride 66 -> <=2-way banks
    __shared__ float2 v2c[4][64];          // per-wave v copy (no cross-wave dep)
    __shared__ float2 w2c[4][64];          // per-wave w copy
    __shared__ float2 pw[64];              // p, shared across waves
    __shared__ float  esq[64];

    const int tid  = threadIdx.x;
    const int b    = blockIdx.x;
    const int lane = tid & 63;
    const int wv   = tid >> 6;
    const int row  = tid >> 2;             // 0..63
    const int ch   = tid & 3;

    const float2* gb = G + (size_t)b * 4096;
    #pragma unroll
    for (int t = 0; t < 16; ++t) {
        int e = t * 256 + tid;             // coalesced read, 2-way-max LDS write
        GC[(e >> 6) * G2STR + (e & 63)] = gb[e];
    }
    __syncthreads();

    for (int k = 0; k < 62; ++k) {
        const int a = k + 1;

        // ---- phase A: redundant per wave (lane = matrix row) ----
        float2 g = make_float2(0.f, 0.f);
        if (lane >= a) g = GC[lane * G2STR + k];
        float sig = g.x * g.x + g.y * g.y;
        #pragma unroll
        for (int off = 1; off < 64; off <<= 1) sig += __shfl_xor(sig, off, 64);
        float x1r = __shfl(g.x, a, 64);
        float x1i = __shfl(g.y, a, 64);
        float ax1 = sqrtf(x1r * x1r + x1i * x1i);
        float nrm = sqrtf(sig);
        float tau = 0.f, pr = 1.f, pi = 0.f;
        if (sig > 1e-30f) {
            tau = 1.f / (sig + nrm * ax1);
            if (ax1 > 1e-30f) { pr = x1r / ax1; pi = x1i / ax1; }
        }
        float vr = g.x, vi = g.y;
        if (lane == a) { vr += pr * nrm; vi += pi * nrm; }
        if (lane < a)  { vr = 0.f; vi = 0.f; }
        v2c[wv][lane] = make_float2(vr, vi);
        if (tid == 0) esq[a] = sig;
        __builtin_amdgcn_wave_barrier();   // order v2c write -> phase-B read (same wave)

        // ---- phase B: p = tau * G v ; rows x 4-lane teams ----
        float pxr = 0.f, pxi = 0.f;
        if (row >= a) {
            for (int j = a + ch; j < 64; j += 4) {
                float2 gg = GC[row * G2STR + j];
                float2 vj = v2c[wv][j];
                pxr += gg.x * vj.x - gg.y * vj.y;
                pxi += gg.x * vj.y + gg.y * vj.x;
            }
        }
        pxr += __shfl_xor(pxr, 1, 64); pxi += __shfl_xor(pxi, 1, 64);
        pxr += __shfl_xor(pxr, 2, 64); pxi += __shfl_xor(pxi, 2, 64);
        if (ch == 0) pw[row] = make_float2(tau * pxr, tau * pxi);   // rows<a write 0
        __syncthreads();                   // barrier 1: p visible to all waves

        // ---- phase C: redundant per wave; w = p - K v ----
        float2 pl = pw[lane];
        float2 vl = v2c[wv][lane];
        float kp = vl.x * pl.x + vl.y * pl.y;
        #pragma unroll
        for (int off = 1; off < 64; off <<= 1) kp += __shfl_xor(kp, off, 64);
        float K = 0.5f * tau * kp;
        w2c[wv][lane] = make_float2(pl.x - K * vl.x, pl.y - K * vl.y);
        __builtin_amdgcn_wave_barrier();   // order w2c write -> phase-D read (same wave)

        // ---- phase D: G -= v w^H + w v^H on [a..63]^2 ----
        if (row >= a) {
            float2 vi2 = v2c[wv][row], wi2 = w2c[wv][row];
            for (int j = a + ch; j < 64; j += 4) {
                float2 vj = v2c[wv][j], wj = w2c[wv][j];
                float2 gg = GC[row * G2STR + j];
                gg.x -= vi2.x * wj.x + vi2.y * wj.y + wi2.x * vj.x + wi2.y * vj.y;
                gg.y -= vi2.y * wj.x - vi2.x * wj.y + wi2.y * vj.x - wi2.x * vj.y;
                GC[row * G2STR + j] = gg;
            }
        }
        __syncthreads();                   // barrier 2: G updates visible everywhere
    }

    if (tid == 0) {
        float2 g = GC[63 * G2STR + 62];
        esq[63] = g.x * g.x + g.y * g.y;
        esq[0]  = 0.f;
    }
    __syncthreads();

    if (tid < 64) {                        // Sturm bisection, lane t -> t-th eigenvalue
        float lo = -0.02f, hi = 1.02f;
        for (int itb = 0; itb < 30; ++itb) {
            float mid = 0.5f * (lo + hi);
            int cnt = 0;
            float q = GC[0].x - mid;
            cnt += (q < 0.f);
            for (int i = 1; i < 64; ++i) {
                float qp = q;
                float aq = (fabsf(qp) < 1e-18f) ? copysignf(1e-18f, qp) : qp;
                q = GC[i * G2STR + i].x - mid - __fdividef(esq[i], aq);
                cnt += (q < 0.f);
            }
            if (cnt > tid) hi = mid; else lo = mid;
        }
        float lam  = fmaxf(0.5f * (lo + hi), 1e-24f);
        float term = -lam * logf(lam);
        #pragma unroll
        for (int off = 32; off; off >>= 1) term += __shfl_down(term, off, 64);
        if (tid == 0) out[(size_t)b * OUTW + HILB + 1] = sanout(term);
    }
}

// ===================== fallback: round-2 single kernel (used if ws too small) =============
__launch_bounds__(256, 4)
__global__ void qsp_fallback(const float* __restrict__ X,  const float* __restrict__ W1,
                             const float* __restrict__ B1, const float* __restrict__ W2,
                             const float* __restrict__ B2, const float* __restrict__ EP,
                             float* __restrict__ out)
{
    __shared__ float  GR[64 * GSTR];
    __shared__ float  GI[64 * GSTR];
    __shared__ float2 vc2[8][64];
    __shared__ float2 v2c[64];
    __shared__ float2 w2c[64];
    __shared__ float  esq[64];
    __shared__ float  sx[FEAT];
    __shared__ float  sh[48];
    __shared__ float  T8[8];
    __shared__ float  red[4];
    __shared__ float  s_inv2;

    const int tid  = threadIdx.x;
    const int b    = blockIdx.x;
    const int lane = tid & 63;
    const int wv   = tid >> 6;

    sx[tid] = X[b * FEAT + tid];
    __syncthreads();
    if (tid < 48) {
        float acc = B1[tid];
        for (int t = 0; t < FEAT; ++t) acc += sx[t] * W1[t * 48 + tid];
        sh[tid] = tanhf(acc);
    }
    if (tid == 64) {
        float t00r=1.f,t00i=0.f,t01r=0.f,t01i=0.f,t10r=0.f,t10i=0.f,t11r=1.f,t11i=0.f;
        for (int g = 0; g < 33; ++g) {
            int d = g / 11, q = g % 11;
            const float* p = EP + (d * 12 + q) * 4;
            float th = p[0], ph = p[1], la = p[2], ga = p[3];
            float c  = cosf(0.5f * th), sn = sinf(0.5f * th);
            float ephr = cosf(ph), ephi = sinf(ph);
            float elar = cosf(la), elai = sinf(la);
            float egar = cosf(ga), egai = sinf(ga);
            float r00r =  c,          r00i = 0.f;
            float r01r = -elar * sn,  r01i = -elai * sn;
            float r10r =  ephr * sn,  r10i =  ephi * sn;
            float r11r =  egar * c,   r11i =  egai * c;
            float n00r = t00r*r00r - t00i*r00i + t01r*r10r - t01i*r10i;
            float n00i = t00r*r00i + t00i*r00r + t01r*r10i + t01i*r10r;
            float n01r = t00r*r01r - t00i*r01i + t01r*r11r - t01i*r11i;
            float n01i = t00r*r01i + t00i*r01r + t01r*r11i + t01i*r11r;
            float n10r = t10r*r00r - t10i*r00i + t11r*r10r - t11i*r10i;
            float n10i = t10r*r00i + t10i*r00r + t11r*r10i + t11i*r10r;
            float n11r = t10r*r01r - t10i*r01i + t11r*r11r - t11i*r11i;
            float n11i = t10r*r01i + t10i*r01r + t11r*r11i + t11i*r11r;
            t00r=n00r; t00i=n00i; t01r=n01r; t01i=n01i;
            t10r=n10r; t10i=n10i; t11r=n11r; t11i=n11i;
        }
        T8[0]=t00r; T8[1]=t00i; T8[2]=t01r; T8[3]=t01i;
        T8[4]=t10r; T8[5]=t10i; T8[6]=t11r; T8[7]=t11i;
    }
    __syncthreads();

    float accRe[16], accIm[16];
    #pragma unroll
    for (int jj = 0; jj < 16; ++jj) { accRe[jj] = 0.f; accIm[jj] = 0.f; }
    float ssq = 0.f;

    const int part = (tid >> 4) & 1;
    const int lr   = tid >> 5;
    const int c0   = (tid & 15) * 4;

    for (int it = 0; it < 8; ++it) {
        int row = it * 8 + lr;
        int j0  = part * HILB + row * 64 + c0;
        float a0 = B2[j0], a1 = B2[j0+1], a2 = B2[j0+2], a3 = B2[j0+3];
        for (int k = 0; k < 48; ++k) {
            float4 w4 = *(const float4*)(W2 + k * 8192 + j0);
            float hk = sh[k];
            a0 += hk * w4.x; a1 += hk * w4.y;
            a2 += hk * w4.z; a3 += hk * w4.w;
        }
        float* vf = (float*)&vc2[lr][0];
        vf[(c0+0)*2 + part] = a0;
        vf[(c0+1)*2 + part] = a1;
        vf[(c0+2)*2 + part] = a2;
        vf[(c0+3)*2 + part] = a3;
        __syncthreads();

        if (it == 0) {
            if (tid == 0) {
                float2 s0 = vc2[0][0], s1 = vc2[0][1];
                float n0r = s0.x*T8[0] - s0.y*T8[1] + s1.x*T8[4] - s1.y*T8[5];
                float n0i = s0.x*T8[1] + s0.y*T8[0] + s1.x*T8[5] + s1.y*T8[4];
                float n1r = s0.x*T8[2] - s0.y*T8[3] + s1.x*T8[6] - s1.y*T8[7];
                float n1i = s0.x*T8[3] + s0.y*T8[2] + s1.x*T8[7] + s1.y*T8[6];
                vc2[0][0] = make_float2(n0r, n0i);
                vc2[0][1] = make_float2(n1r, n1i);
            }
            __syncthreads();
        }

        #pragma unroll
        for (int s = 0; s < 2; ++s) {
            int jo  = tid + s * 256;
            int lr2 = jo >> 6, cc = jo & 63;
            float2 v = vc2[lr2][cc];
            float praw = v.x * v.x + v.y * v.y;
            out[(size_t)b * OUTW + it * 512 + jo] = praw;
            ssq += praw;
        }

        for (int rr = 0; rr < 8; ++rr) {
            float2 vq = vc2[rr][lane];
            #pragma unroll
            for (int jj = 0; jj < 16; ++jj) {
                float2 vp = vc2[rr][wv * 16 + jj];
                accRe[jj] += vp.x * vq.x + vp.y * vq.y;
                accIm[jj] += vp.x * vq.y - vp.y * vq.x;
            }
        }
        __syncthreads();
    }

    {
        float v = ssq;
        #pragma unroll
        for (int off = 32; off; off >>= 1) v += __shfl_down(v, off, 64);
        if (lane == 0) red[wv] = v;
        __syncthreads();
        if (tid == 0) {
            float tot = red[0] + red[1] + red[2] + red[3];
            float nrm = sqrtf(tot);
            float inv = 1.f / fmaxf(nrm, 1e-12f);
            float i2  = inv * inv;
            s_inv2 = i2;
            float n2  = tot * i2;
            float lam = fmaxf(n2, 1e-12f);
            out[(size_t)b * OUTW + HILB] = sanout(-lam * logf(lam) + 1.1314877e-7f);
        }
        __syncthreads();
    }
    const float inv2 = s_inv2;

    #pragma unroll
    for (int i = 0; i < 16; ++i) {
        size_t idx = (size_t)b * OUTW + (i >> 1) * 512 + (i & 1) * 256 + tid;
        out[idx] = sanout(inv2 * out[idx]);
    }

    #pragma unroll
    for (int jj = 0; jj < 16; ++jj) {
        int p = wv * 16 + jj;
        GR[p * GSTR + lane] = inv2 * accRe[jj];
        GI[p * GSTR + lane] = inv2 * accIm[jj];
    }
    __syncthreads();
    if (wv != 0) return;

    const int ib = lane * GSTR;
    for (int k = 0; k < 62; ++k) {
        const int a = k + 1;
        float gr = 0.f, gi = 0.f;
        if (lane >= a) { gr = GR[ib + k]; gi = GI[ib + k]; }
        float sig = gr * gr + gi * gi;
        #pragma unroll
        for (int off = 1; off < 64; off <<= 1) sig += __shfl_xor(sig, off, 64);
        float x1r = __shfl(gr, a, 64);
        float x1i = __shfl(gi, a, 64);
        float ax1 = sqrtf(x1r * x1r + x1i * x1i);
        float nrm = sqrtf(sig);
        float tau = 0.f, pr = 1.f, pi = 0.f;
        if (sig > 1e-30f) {
            tau = 1.f / (sig + nrm * ax1);
            if (ax1 > 1e-30f) { pr = x1r / ax1; pi = x1i / ax1; }
        }
        float vr = gr, vi = gi;
        if (lane == a) { vr += pr * nrm; vi += pi * nrm; }
        if (lane < a)  { vr = 0.f; vi = 0.f; }
        v2c[lane] = make_float2(vr, vi);
        if (lane == 0) esq[a] = sig;
        __builtin_amdgcn_wave_barrier();

        float pxr = 0.f, pxi = 0.f;
        if (lane >= a) {
            for (int j = a; j < 64; ++j) {
                float grj = GR[ib + j], gij = GI[ib + j];
                float2 vj = v2c[j];
                pxr += grj * vj.x - gij * vj.y;
                pxi += grj * vj.y + gij * vj.x;
            }
            pxr *= tau; pxi *= tau;
        }

        float kp = vr * pxr + vi * pxi;
        #pragma unroll
        for (int off = 1; off < 64; off <<= 1) kp += __shfl_xor(kp, off, 64);
        float K  = 0.5f * tau * kp;
        float wr = pxr - K * vr, wi = pxi - K * vi;
        w2c[lane] = make_float2(wr, wi);
        __builtin_amdgcn_wave_barrier();

        if (lane >= a) {
            for (int j = a; j < 64; ++j) {
                float2 vj = v2c[j], wj = w2c[j];
                float grj = GR[ib + j], gij = GI[ib + j];
                grj -= vr * wj.x + vi * wj.y + wr * vj.x + wi * vj.y;
                gij -= vi * wj.x - vr * wj.y + wi * vj.x - wr * vj.y;
                GR[ib + j] = grj; GI[ib + j] = gij;
            }
        }
        __builtin_amdgcn_wave_barrier();
    }

    if (lane == 0) {
        float gx = GR[63 * GSTR + 62], gy = GI[63 * GSTR + 62];
        esq[63] = gx * gx + gy * gy;
        esq[0]  = 0.f;
    }
    __builtin_amdgcn_wave_barrier();

    {
        float lo = -0.02f, hi = 1.02f;
        for (int itb = 0; itb < 30; ++itb) {
            float mid = 0.5f * (lo + hi);
            int cnt = 0;
            float q = GR[0] - mid;
            cnt += (q < 0.f);
            for (int i = 1; i < 64; ++i) {
                float qp = q;
                float aq = (fabsf(qp) < 1e-18f) ? copysignf(1e-18f, qp) : qp;
                q = GR[i * GSTR + i] - mid - __fdividef(esq[i], aq);
                cnt += (q < 0.f);
            }
            if (cnt > lane) hi = mid; else lo = mid;
        }
        float lam  = fmaxf(0.5f * (lo + hi), 1e-24f);
        float term = -lam * logf(lam);
        #pragma unroll
        for (int off = 32; off; off >>= 1) term += __shfl_down(term, off, 64);
        if (lane == 0) out[(size_t)b * OUTW + HILB + 1] = sanout(term);
    }
}

extern "C" void kernel_launch(void* const* d_in, const int* in_sizes, int n_in,
                              void* d_out, int out_size, void* d_ws, size_t ws_size,
                              hipStream_t stream) {
    const float* X  = (const float*)d_in[0];
    const float* W1 = (const float*)d_in[1];
    const float* B1 = (const float*)d_in[2];
    const float* W2 = (const float*)d_in[3];
    const float* B2 = (const float*)d_in[4];
    const float* EP = (const float*)d_in[5];
    const size_t G_BYTES = (size_t)4096 * 4096 * sizeof(float2);   // 134.2 MB
    if (d_ws != nullptr && ws_size >= G_BYTES) {
        float2* G = (float2*)d_ws;
        qsp_front<<<dim3(4096), dim3(256), 0, stream>>>(X, W1, B1, W2, B2, EP,
                                                        (float*)d_out, G);
        eig_kernel<<<dim3(4096), dim3(256), 0, stream>>>(G, (float*)d_out);
    } else {
        qsp_fallback<<<dim3(4096), dim3(256), 0, stream>>>(X, W1, B1, W2, B2, EP,
                                                           (float*)d_out);
    }
}

// Round 4
// 1978.620 us; speedup vs baseline: 2.5396x; 2.5396x over previous
//
#include <hip/hip_runtime.h>
#include <math.h>

#define HILB  4096
#define FEAT  256
#define OUTW  4098          // 4096 probs + entropy + entangle
#define GSTR  65            // planar G row stride (fallback kernel)

__device__ __forceinline__ float sanout(float v) {
    return (v == v && fabsf(v) < 1e30f) ? v : 1e6f;  // readable failure signature
}

// ===================== kernel 1: front (h, gates, amps, probs, entropy, G -> ws) ==========
__launch_bounds__(256, 4)
__global__ void qsp_front(const float* __restrict__ X,  const float* __restrict__ W1,
                          const float* __restrict__ B1, const float* __restrict__ W2,
                          const float* __restrict__ B2, const float* __restrict__ EP,
                          float* __restrict__ out, float2* __restrict__ G)
{
    __shared__ float2 vc2[8][64];          // 8 rows of M staging
    __shared__ float  sx[FEAT];
    __shared__ float  sh[48];
    __shared__ float  T8[8];
    __shared__ float  red[4];
    __shared__ float  s_inv2;

    const int tid  = threadIdx.x;
    const int b    = blockIdx.x;
    const int lane = tid & 63;
    const int wv   = tid >> 6;

    sx[tid] = X[b * FEAT + tid];
    __syncthreads();
    if (tid < 48) {
        float acc = B1[tid];
        for (int t = 0; t < FEAT; ++t) acc += sx[t] * W1[t * 48 + tid];
        sh[tid] = tanhf(acc);
    }
    if (tid == 64) {   // gate product on one thread of wave 1 (overlaps with h)
        float t00r=1.f,t00i=0.f,t01r=0.f,t01i=0.f,t10r=0.f,t10i=0.f,t11r=1.f,t11i=0.f;
        for (int g = 0; g < 33; ++g) {
            int d = g / 11, q = g % 11;
            const float* p = EP + (d * 12 + q) * 4;
            float th = p[0], ph = p[1], la = p[2], ga = p[3];
            float c  = cosf(0.5f * th), sn = sinf(0.5f * th);
            float ephr = cosf(ph), ephi = sinf(ph);
            float elar = cosf(la), elai = sinf(la);
            float egar = cosf(ga), egai = sinf(ga);
            float r00r =  c,          r00i = 0.f;
            float r01r = -elar * sn,  r01i = -elai * sn;
            float r10r =  ephr * sn,  r10i =  ephi * sn;
            float r11r =  egar * c,   r11i =  egai * c;
            float n00r = t00r*r00r - t00i*r00i + t01r*r10r - t01i*r10i;
            float n00i = t00r*r00i + t00i*r00r + t01r*r10i + t01i*r10r;
            float n01r = t00r*r01r - t00i*r01i + t01r*r11r - t01i*r11i;
            float n01i = t00r*r01i + t00i*r01r + t01r*r11i + t01i*r11r;
            float n10r = t10r*r00r - t10i*r00i + t11r*r10r - t11i*r10i;
            float n10i = t10r*r00i + t10i*r00r + t11r*r10i + t11i*r10r;
            float n11r = t10r*r01r - t10i*r01i + t11r*r11r - t11i*r11i;
            float n11i = t10r*r01i + t10i*r01r + t11r*r11i + t11i*r11r;
            t00r=n00r; t00i=n00i; t01r=n01r; t01i=n01i;
            t10r=n10r; t10i=n10i; t11r=n11r; t11i=n11i;
        }
        T8[0]=t00r; T8[1]=t00i; T8[2]=t01r; T8[3]=t01i;
        T8[4]=t10r; T8[5]=t10i; T8[6]=t11r; T8[7]=t11i;
    }
    __syncthreads();

    float accRe[16], accIm[16];
    #pragma unroll
    for (int jj = 0; jj < 16; ++jj) { accRe[jj] = 0.f; accIm[jj] = 0.f; }
    float ssq = 0.f;

    const int part = (tid >> 4) & 1;
    const int lr   = tid >> 5;
    const int c0   = (tid & 15) * 4;

    for (int it = 0; it < 8; ++it) {
        int row = it * 8 + lr;
        int j0  = part * HILB + row * 64 + c0;
        float a0 = B2[j0], a1 = B2[j0+1], a2 = B2[j0+2], a3 = B2[j0+3];
        #pragma unroll 8
        for (int k = 0; k < 48; ++k) {     // unroll-8: 8 W2 loads in flight (L2-latency hiding)
            float4 w4 = *(const float4*)(W2 + k * 8192 + j0);
            float hk = sh[k];
            a0 += hk * w4.x; a1 += hk * w4.y;
            a2 += hk * w4.z; a3 += hk * w4.w;
        }
        float* vf = (float*)&vc2[lr][0];
        vf[(c0+0)*2 + part] = a0;
        vf[(c0+1)*2 + part] = a1;
        vf[(c0+2)*2 + part] = a2;
        vf[(c0+3)*2 + part] = a3;
        __syncthreads();

        if (it == 0) {                     // apply gate product T to raw psi0, psi1
            if (tid == 0) {
                float2 s0 = vc2[0][0], s1 = vc2[0][1];
                float n0r = s0.x*T8[0] - s0.y*T8[1] + s1.x*T8[4] - s1.y*T8[5];
                float n0i = s0.x*T8[1] + s0.y*T8[0] + s1.x*T8[5] + s1.y*T8[4];
                float n1r = s0.x*T8[2] - s0.y*T8[3] + s1.x*T8[6] - s1.y*T8[7];
                float n1i = s0.x*T8[3] + s0.y*T8[2] + s1.x*T8[7] + s1.y*T8[6];
                vc2[0][0] = make_float2(n0r, n0i);
                vc2[0][1] = make_float2(n1r, n1i);
            }
            __syncthreads();
        }

        #pragma unroll
        for (int s = 0; s < 2; ++s) {      // raw probs out; rescaled after norm
            int jo  = tid + s * 256;
            int lr2 = jo >> 6, cc = jo & 63;
            float2 v = vc2[lr2][cc];
            float praw = v.x * v.x + v.y * v.y;
            out[(size_t)b * OUTW + it * 512 + jo] = praw;
            ssq += praw;
        }

        for (int rr = 0; rr < 8; ++rr) {   // raw Gram accumulation
            float2 vq = vc2[rr][lane];
            #pragma unroll
            for (int jj = 0; jj < 16; ++jj) {
                float2 vp = vc2[rr][wv * 16 + jj];
                accRe[jj] += vp.x * vq.x + vp.y * vq.y;
                accIm[jj] += vp.x * vq.y - vp.y * vq.x;
            }
        }
        __syncthreads();
    }

    // norm -> inv2, entropy
    {
        float v = ssq;
        #pragma unroll
        for (int off = 32; off; off >>= 1) v += __shfl_down(v, off, 64);
        if (lane == 0) red[wv] = v;
        __syncthreads();
        if (tid == 0) {
            float tot = red[0] + red[1] + red[2] + red[3];
            float nrm = sqrtf(tot);
            float inv = 1.f / fmaxf(nrm, 1e-12f);
            float i2  = inv * inv;
            s_inv2 = i2;
            float n2  = tot * i2;
            float lam = fmaxf(n2, 1e-12f);
            out[(size_t)b * OUTW + HILB] = sanout(-lam * logf(lam) + 1.1314877e-7f);
        }
        __syncthreads();
    }
    const float inv2 = s_inv2;

    // scaled G straight from registers to workspace (coalesced float2)
    float2* gb = G + (size_t)b * 4096;
    #pragma unroll
    for (int jj = 0; jj < 16; ++jj) {
        int p = wv * 16 + jj;
        gb[p * 64 + lane] = make_float2(inv2 * accRe[jj], inv2 * accIm[jj]);
    }

    // rescale own prob slots (same-thread RAW)
    #pragma unroll
    for (int i = 0; i < 16; ++i) {
        size_t idx = (size_t)b * OUTW + (i >> 1) * 512 + (i & 1) * 256 + tid;
        out[idx] = sanout(inv2 * out[idx]);
    }
}

// ===================== kernel 2: eigensolve — G in registers, 1 wave per block ============
// lane <-> matrix row; each lane holds its full row (gr[64]/gi[64], static indexing only).
// v/w broadcast through 1.5 KB LDS; column k+1 extracted with static-j compare in phase D.
// Unguarded j-loops are exact: v[j<a]=0 and w masked to 0 for lanes<a, so dead terms are 0.
#define EIG_STEP(J0)                                                                 \
{                                                                                    \
    const int a = k + 1;                                                             \
    float cr = (lane >= a) ? ncr : 0.f;                                              \
    float ci = (lane >= a) ? nci : 0.f;                                              \
    float sig = cr * cr + ci * ci;                                                   \
    _Pragma("unroll")                                                                \
    for (int off = 1; off < 64; off <<= 1) sig += __shfl_xor(sig, off, 64);          \
    float x1r = __shfl(cr, a, 64);                                                   \
    float x1i = __shfl(ci, a, 64);                                                   \
    float ax1 = sqrtf(x1r * x1r + x1i * x1i);                                        \
    float nrmv = sqrtf(sig);                                                         \
    float tau = 0.f, prr = 1.f, pii = 0.f;                                           \
    if (sig > 1e-30f) {                                                              \
        tau = 1.f / (sig + nrmv * ax1);                                              \
        if (ax1 > 1e-30f) { prr = x1r / ax1; pii = x1i / ax1; }                      \
    }                                                                                \
    float vr = cr, vi = ci;                                                          \
    if (lane == a) { vr += prr * nrmv; vi += pii * nrmv; }                           \
    vlds[lane] = make_float2(vr, vi);                                                \
    if (lane == 0) eslds[a] = sig;                                                   \
    __builtin_amdgcn_wave_barrier();                                                 \
    /* phase B: p_row = tau * sum_j G[row][j] v[j] (2 indep chains) */               \
    float p0r = 0.f, p0i = 0.f, p1r = 0.f, p1i = 0.f;                                \
    _Pragma("unroll")                                                                \
    for (int j = J0; j < 64; j += 2) {                                               \
        float2 vj0 = vlds[j];                                                        \
        p0r += gr[j] * vj0.x - gi[j] * vj0.y;                                        \
        p0i += gr[j] * vj0.y + gi[j] * vj0.x;                                        \
        float2 vj1 = vlds[j + 1];                                                    \
        p1r += gr[j + 1] * vj1.x - gi[j + 1] * vj1.y;                                \
        p1i += gr[j + 1] * vj1.y + gi[j + 1] * vj1.x;                                \
    }                                                                                \
    float pxr = tau * (p0r + p1r), pxi = tau * (p0i + p1i);                          \
    /* phase C: K = (tau/2) Re(v^H p); w = p - K v; mask lanes<a to keep G exact */  \
    float kp = vr * pxr + vi * pxi;                                                  \
    _Pragma("unroll")                                                                \
    for (int off = 1; off < 64; off <<= 1) kp += __shfl_xor(kp, off, 64);            \
    float K  = 0.5f * tau * kp;                                                      \
    float wr = pxr - K * vr, wi = pxi - K * vi;                                      \
    if (lane < a) { wr = 0.f; wi = 0.f; }                                            \
    vwlds[lane] = make_float4(vr, vi, wr, wi);                                       \
    __builtin_amdgcn_wave_barrier();                                                 \
    /* phase D: G[row][j] -= v_row conj(w_j) + w_row conj(v_j); grab column a */     \
    _Pragma("unroll")                                                                \
    for (int j = J0; j < 64; ++j) {                                                  \
        float4 q = vwlds[j];                                                         \
        gr[j] -= vr * q.z + vi * q.w + wr * q.x + wi * q.y;                          \
        gi[j] -= vi * q.z - vr * q.w + wi * q.x - wr * q.y;                          \
        if (j == a) { ncr = gr[j]; nci = gi[j]; }                                    \
    }                                                                                \
    __builtin_amdgcn_wave_barrier();                                                 \
}

__launch_bounds__(64, 2)
__global__ void eig_kernel(const float2* __restrict__ G, float* __restrict__ out)
{
    __shared__ float2 vlds[64];            // v broadcast
    __shared__ float4 vwlds[64];           // (v, w) combined for phase D
    __shared__ float  eslds[64];           // |subdiag|^2
    __shared__ float  dlds[64];            // tridiagonal diagonal

    const int lane = threadIdx.x;          // 64-thread block = 1 wave
    const int b    = blockIdx.x;

    float gr[64], gi[64];
    const float4* grow = (const float4*)(G + (size_t)b * 4096 + lane * 64);
    #pragma unroll
    for (int t = 0; t < 32; ++t) {         // lane's own row -> registers (static idx)
        float4 q = grow[t];
        gr[2*t]   = q.x; gi[2*t]   = q.y;
        gr[2*t+1] = q.z; gi[2*t+1] = q.w;
    }
    if (lane == 0) eslds[0] = 0.f;

    float ncr = gr[0], nci = gi[0];        // column 0 (pre-step state)

    for (int k = 0;  k < 16; ++k) EIG_STEP(0)
    for (int k = 16; k < 32; ++k) EIG_STEP(16)
    for (int k = 32; k < 48; ++k) EIG_STEP(32)
    for (int k = 48; k < 62; ++k) EIG_STEP(48)

    // diagonal + last subdiag -> LDS for Sturm
    {
        float dval = 0.f;
        #pragma unroll
        for (int j = 0; j < 64; ++j) if (j == lane) dval = gr[j];
        dlds[lane] = dval;
        if (lane == 63) eslds[63] = gr[62] * gr[62] + gi[62] * gi[62];
    }
    __builtin_amdgcn_wave_barrier();

    // Sturm bisection: lane t finds t-th smallest eigenvalue (broadcast LDS reads)
    float lo = -0.02f, hi = 1.02f;
    for (int itb = 0; itb < 30; ++itb) {
        float mid = 0.5f * (lo + hi);
        int cnt = 0;
        float q = dlds[0] - mid;
        cnt += (q < 0.f);
        for (int i = 1; i < 64; ++i) {
            float qp = q;
            float aq = (fabsf(qp) < 1e-18f) ? copysignf(1e-18f, qp) : qp;
            q = dlds[i] - mid - __fdividef(eslds[i], aq);
            cnt += (q < 0.f);
        }
        if (cnt > lane) hi = mid; else lo = mid;
    }
    float lam  = fmaxf(0.5f * (lo + hi), 1e-24f);
    float term = -lam * logf(lam);
    #pragma unroll
    for (int off = 32; off; off >>= 1) term += __shfl_down(term, off, 64);
    if (lane == 0) out[(size_t)b * OUTW + HILB + 1] = sanout(term);
}

// ===================== fallback: round-2 single kernel (used if ws too small) =============
__launch_bounds__(256, 4)
__global__ void qsp_fallback(const float* __restrict__ X,  const float* __restrict__ W1,
                             const float* __restrict__ B1, const float* __restrict__ W2,
                             const float* __restrict__ B2, const float* __restrict__ EP,
                             float* __restrict__ out)
{
    __shared__ float  GR[64 * GSTR];
    __shared__ float  GI[64 * GSTR];
    __shared__ float2 vc2[8][64];
    __shared__ float2 v2c[64];
    __shared__ float2 w2c[64];
    __shared__ float  esq[64];
    __shared__ float  sx[FEAT];
    __shared__ float  sh[48];
    __shared__ float  T8[8];
    __shared__ float  red[4];
    __shared__ float  s_inv2;

    const int tid  = threadIdx.x;
    const int b    = blockIdx.x;
    const int lane = tid & 63;
    const int wv   = tid >> 6;

    sx[tid] = X[b * FEAT + tid];
    __syncthreads();
    if (tid < 48) {
        float acc = B1[tid];
        for (int t = 0; t < FEAT; ++t) acc += sx[t] * W1[t * 48 + tid];
        sh[tid] = tanhf(acc);
    }
    if (tid == 64) {
        float t00r=1.f,t00i=0.f,t01r=0.f,t01i=0.f,t10r=0.f,t10i=0.f,t11r=1.f,t11i=0.f;
        for (int g = 0; g < 33; ++g) {
            int d = g / 11, q = g % 11;
            const float* p = EP + (d * 12 + q) * 4;
            float th = p[0], ph = p[1], la = p[2], ga = p[3];
            float c  = cosf(0.5f * th), sn = sinf(0.5f * th);
            float ephr = cosf(ph), ephi = sinf(ph);
            float elar = cosf(la), elai = sinf(la);
            float egar = cosf(ga), egai = sinf(ga);
            float r00r =  c,          r00i = 0.f;
            float r01r = -elar * sn,  r01i = -elai * sn;
            float r10r =  ephr * sn,  r10i =  ephi * sn;
            float r11r =  egar * c,   r11i =  egai * c;
            float n00r = t00r*r00r - t00i*r00i + t01r*r10r - t01i*r10i;
            float n00i = t00r*r00i + t00i*r00r + t01r*r10i + t01i*r10r;
            float n01r = t00r*r01r - t00i*r01i + t01r*r11r - t01i*r11i;
            float n01i = t00r*r01i + t00i*r01r + t01r*r11i + t01i*r11r;
            float n10r = t10r*r00r - t10i*r00i + t11r*r10r - t11i*r10i;
            float n10i = t10r*r00i + t10i*r00r + t11r*r10i + t11i*r10r;
            float n11r = t10r*r01r - t10i*r01i + t11r*r11r - t11i*r11i;
            float n11i = t10r*r01i + t10i*r01r + t11r*r11i + t11i*r11r;
            t00r=n00r; t00i=n00i; t01r=n01r; t01i=n01i;
            t10r=n10r; t10i=n10i; t11r=n11r; t11i=n11i;
        }
        T8[0]=t00r; T8[1]=t00i; T8[2]=t01r; T8[3]=t01i;
        T8[4]=t10r; T8[5]=t10i; T8[6]=t11r; T8[7]=t11i;
    }
    __syncthreads();

    float accRe[16], accIm[16];
    #pragma unroll
    for (int jj = 0; jj < 16; ++jj) { accRe[jj] = 0.f; accIm[jj] = 0.f; }
    float ssq = 0.f;

    const int part = (tid >> 4) & 1;
    const int lr   = tid >> 5;
    const int c0   = (tid & 15) * 4;

    for (int it = 0; it < 8; ++it) {
        int row = it * 8 + lr;
        int j0  = part * HILB + row * 64 + c0;
        float a0 = B2[j0], a1 = B2[j0+1], a2 = B2[j0+2], a3 = B2[j0+3];
        for (int k = 0; k < 48; ++k) {
            float4 w4 = *(const float4*)(W2 + k * 8192 + j0);
            float hk = sh[k];
            a0 += hk * w4.x; a1 += hk * w4.y;
            a2 += hk * w4.z; a3 += hk * w4.w;
        }
        float* vf = (float*)&vc2[lr][0];
        vf[(c0+0)*2 + part] = a0;
        vf[(c0+1)*2 + part] = a1;
        vf[(c0+2)*2 + part] = a2;
        vf[(c0+3)*2 + part] = a3;
        __syncthreads();

        if (it == 0) {
            if (tid == 0) {
                float2 s0 = vc2[0][0], s1 = vc2[0][1];
                float n0r = s0.x*T8[0] - s0.y*T8[1] + s1.x*T8[4] - s1.y*T8[5];
                float n0i = s0.x*T8[1] + s0.y*T8[0] + s1.x*T8[5] + s1.y*T8[4];
                float n1r = s0.x*T8[2] - s0.y*T8[3] + s1.x*T8[6] - s1.y*T8[7];
                float n1i = s0.x*T8[3] + s0.y*T8[2] + s1.x*T8[7] + s1.y*T8[6];
                vc2[0][0] = make_float2(n0r, n0i);
                vc2[0][1] = make_float2(n1r, n1i);
            }
            __syncthreads();
        }

        #pragma unroll
        for (int s = 0; s < 2; ++s) {
            int jo  = tid + s * 256;
            int lr2 = jo >> 6, cc = jo & 63;
            float2 v = vc2[lr2][cc];
            float praw = v.x * v.x + v.y * v.y;
            out[(size_t)b * OUTW + it * 512 + jo] = praw;
            ssq += praw;
        }

        for (int rr = 0; rr < 8; ++rr) {
            float2 vq = vc2[rr][lane];
            #pragma unroll
            for (int jj = 0; jj < 16; ++jj) {
                float2 vp = vc2[rr][wv * 16 + jj];
                accRe[jj] += vp.x * vq.x + vp.y * vq.y;
                accIm[jj] += vp.x * vq.y - vp.y * vq.x;
            }
        }
        __syncthreads();
    }

    {
        float v = ssq;
        #pragma unroll
        for (int off = 32; off; off >>= 1) v += __shfl_down(v, off, 64);
        if (lane == 0) red[wv] = v;
        __syncthreads();
        if (tid == 0) {
            float tot = red[0] + red[1] + red[2] + red[3];
            float nrm = sqrtf(tot);
            float inv = 1.f / fmaxf(nrm, 1e-12f);
            float i2  = inv * inv;
            s_inv2 = i2;
            float n2  = tot * i2;
            float lam = fmaxf(n2, 1e-12f);
            out[(size_t)b * OUTW + HILB] = sanout(-lam * logf(lam) + 1.1314877e-7f);
        }
        __syncthreads();
    }
    const float inv2 = s_inv2;

    #pragma unroll
    for (int i = 0; i < 16; ++i) {
        size_t idx = (size_t)b * OUTW + (i >> 1) * 512 + (i & 1) * 256 + tid;
        out[idx] = sanout(inv2 * out[idx]);
    }

    #pragma unroll
    for (int jj = 0; jj < 16; ++jj) {
        int p = wv * 16 + jj;
        GR[p * GSTR + lane] = inv2 * accRe[jj];
        GI[p * GSTR + lane] = inv2 * accIm[jj];
    }
    __syncthreads();
    if (wv != 0) return;

    const int ib = lane * GSTR;
    for (int k = 0; k < 62; ++k) {
        const int a = k + 1;
        float grv = 0.f, giv = 0.f;
        if (lane >= a) { grv = GR[ib + k]; giv = GI[ib + k]; }
        float sig = grv * grv + giv * giv;
        #pragma unroll
        for (int off = 1; off < 64; off <<= 1) sig += __shfl_xor(sig, off, 64);
        float x1r = __shfl(grv, a, 64);
        float x1i = __shfl(giv, a, 64);
        float ax1 = sqrtf(x1r * x1r + x1i * x1i);
        float nrm = sqrtf(sig);
        float tau = 0.f, pr = 1.f, pi = 0.f;
        if (sig > 1e-30f) {
            tau = 1.f / (sig + nrm * ax1);
            if (ax1 > 1e-30f) { pr = x1r / ax1; pi = x1i / ax1; }
        }
        float vr = grv, vi = giv;
        if (lane == a) { vr += pr * nrm; vi += pi * nrm; }
        if (lane < a)  { vr = 0.f; vi = 0.f; }
        v2c[lane] = make_float2(vr, vi);
        if (lane == 0) esq[a] = sig;
        __builtin_amdgcn_wave_barrier();

        float pxr = 0.f, pxi = 0.f;
        if (lane >= a) {
            for (int j = a; j < 64; ++j) {
                float grj = GR[ib + j], gij = GI[ib + j];
                float2 vj = v2c[j];
                pxr += grj * vj.x - gij * vj.y;
                pxi += grj * vj.y + gij * vj.x;
            }
            pxr *= tau; pxi *= tau;
        }

        float kp = vr * pxr + vi * pxi;
        #pragma unroll
        for (int off = 1; off < 64; off <<= 1) kp += __shfl_xor(kp, off, 64);
        float K  = 0.5f * tau * kp;
        float wr = pxr - K * vr, wi = pxi - K * vi;
        w2c[lane] = make_float2(wr, wi);
        __builtin_amdgcn_wave_barrier();

        if (lane >= a) {
            for (int j = a; j < 64; ++j) {
                float2 vj = v2c[j], wj = w2c[j];
                float grj = GR[ib + j], gij = GI[ib + j];
                grj -= vr * wj.x + vi * wj.y + wr * vj.x + wi * vj.y;
                gij -= vi * wj.x - vr * wj.y + wi * vj.x - wr * vj.y;
                GR[ib + j] = grj; GI[ib + j] = gij;
            }
        }
        __builtin_amdgcn_wave_barrier();
    }

    if (lane == 0) {
        float gx = GR[63 * GSTR + 62], gy = GI[63 * GSTR + 62];
        esq[63] = gx * gx + gy * gy;
        esq[0]  = 0.f;
    }
    __builtin_amdgcn_wave_barrier();

    {
        float lo = -0.02f, hi = 1.02f;
        for (int itb = 0; itb < 30; ++itb) {
            float mid = 0.5f * (lo + hi);
            int cnt = 0;
            float q = GR[0] - mid;
            cnt += (q < 0.f);
            for (int i = 1; i < 64; ++i) {
                float qp = q;
                float aq = (fabsf(qp) < 1e-18f) ? copysignf(1e-18f, qp) : qp;
                q = GR[i * GSTR + i] - mid - __fdividef(esq[i], aq);
                cnt += (q < 0.f);
            }
            if (cnt > lane) hi = mid; else lo = mid;
        }
        float lam  = fmaxf(0.5f * (lo + hi), 1e-24f);
        float term = -lam * logf(lam);
        #pragma unroll
        for (int off = 32; off; off >>= 1) term += __shfl_down(term, off, 64);
        if (lane == 0) out[(size_t)b * OUTW + HILB + 1] = sanout(term);
    }
}

extern "C" void kernel_launch(void* const* d_in, const int* in_sizes, int n_in,
                              void* d_out, int out_size, void* d_ws, size_t ws_size,
                              hipStream_t stream) {
    const float* X  = (const float*)d_in[0];
    const float* W1 = (const float*)d_in[1];
    const float* B1 = (const float*)d_in[2];
    const float* W2 = (const float*)d_in[3];
    const float* B2 = (const float*)d_in[4];
    const float* EP = (const float*)d_in[5];
    const size_t G_BYTES = (size_t)4096 * 4096 * sizeof(float2);   // 134.2 MB
    if (d_ws != nullptr && ws_size >= G_BYTES) {
        float2* G = (float2*)d_ws;
        qsp_front<<<dim3(4096), dim3(256), 0, stream>>>(X, W1, B1, W2, B2, EP,
                                                        (float*)d_out, G);
        eig_kernel<<<dim3(4096), dim3(64), 0, stream>>>(G, (float*)d_out);
    } else {
        qsp_fallback<<<dim3(4096), dim3(256), 0, stream>>>(X, W1, B1, W2, B2, EP,
                                                           (float*)d_out);
    }
}

// Round 5
// 1509.025 us; speedup vs baseline: 3.3299x; 1.3112x over previous
//
#include <hip/hip_runtime.h>
#include <math.h>

#define HILB  4096
#define FEAT  256
#define OUTW  4098          // 4096 probs + entropy + entangle
#define GSTR  65            // planar G row stride (fallback kernel)

__device__ __forceinline__ float sanout(float v) {
    return (v == v && fabsf(v) < 1e30f) ? v : 1e6f;  // readable failure signature
}

// ===================== kernel 1: front (h, gates, amps, probs, entropy, G -> ws) ==========
__launch_bounds__(256, 4)
__global__ void qsp_front(const float* __restrict__ X,  const float* __restrict__ W1,
                          const float* __restrict__ B1, const float* __restrict__ W2,
                          const float* __restrict__ B2, const float* __restrict__ EP,
                          float* __restrict__ out, float2* __restrict__ G)
{
    __shared__ float2 vc2[8][64];          // 8 rows of M staging
    __shared__ float  sx[FEAT];
    __shared__ float  sh[48];
    __shared__ float  T8[8];
    __shared__ float  red[4];
    __shared__ float  s_inv2;

    const int tid  = threadIdx.x;
    const int b    = blockIdx.x;
    const int lane = tid & 63;
    const int wv   = tid >> 6;

    sx[tid] = X[b * FEAT + tid];
    __syncthreads();
    if (tid < 48) {
        float acc = B1[tid];
        for (int t = 0; t < FEAT; ++t) acc += sx[t] * W1[t * 48 + tid];
        sh[tid] = tanhf(acc);
    }
    if (tid == 64) {   // gate product on one thread of wave 1 (overlaps with h)
        float t00r=1.f,t00i=0.f,t01r=0.f,t01i=0.f,t10r=0.f,t10i=0.f,t11r=1.f,t11i=0.f;
        for (int g = 0; g < 33; ++g) {
            int d = g / 11, q = g % 11;
            const float* p = EP + (d * 12 + q) * 4;
            float th = p[0], ph = p[1], la = p[2], ga = p[3];
            float c  = cosf(0.5f * th), sn = sinf(0.5f * th);
            float ephr = cosf(ph), ephi = sinf(ph);
            float elar = cosf(la), elai = sinf(la);
            float egar = cosf(ga), egai = sinf(ga);
            float r00r =  c,          r00i = 0.f;
            float r01r = -elar * sn,  r01i = -elai * sn;
            float r10r =  ephr * sn,  r10i =  ephi * sn;
            float r11r =  egar * c,   r11i =  egai * c;
            float n00r = t00r*r00r - t00i*r00i + t01r*r10r - t01i*r10i;
            float n00i = t00r*r00i + t00i*r00r + t01r*r10i + t01i*r10r;
            float n01r = t00r*r01r - t00i*r01i + t01r*r11r - t01i*r11i;
            float n01i = t00r*r01i + t00i*r01r + t01r*r11i + t01i*r11r;
            float n10r = t10r*r00r - t10i*r00i + t11r*r10r - t11i*r10i;
            float n10i = t10r*r00i + t10i*r00r + t11r*r10i + t11i*r10r;
            float n11r = t10r*r01r - t10i*r01i + t11r*r11r - t11i*r11i;
            float n11i = t10r*r01i + t10i*r01r + t11r*r11i + t11i*r11r;
            t00r=n00r; t00i=n00i; t01r=n01r; t01i=n01i;
            t10r=n10r; t10i=n10i; t11r=n11r; t11i=n11i;
        }
        T8[0]=t00r; T8[1]=t00i; T8[2]=t01r; T8[3]=t01i;
        T8[4]=t10r; T8[5]=t10i; T8[6]=t11r; T8[7]=t11i;
    }
    __syncthreads();

    float accRe[16], accIm[16];
    #pragma unroll
    for (int jj = 0; jj < 16; ++jj) { accRe[jj] = 0.f; accIm[jj] = 0.f; }
    float ssq = 0.f;

    const int part = (tid >> 4) & 1;
    const int lr   = tid >> 5;
    const int c0   = (tid & 15) * 4;

    for (int it = 0; it < 8; ++it) {
        int row = it * 8 + lr;
        int j0  = part * HILB + row * 64 + c0;
        float a0 = B2[j0], a1 = B2[j0+1], a2 = B2[j0+2], a3 = B2[j0+3];
        #pragma unroll 8
        for (int k = 0; k < 48; ++k) {     // unroll-8: 8 W2 loads in flight (L2-latency hiding)
            float4 w4 = *(const float4*)(W2 + k * 8192 + j0);
            float hk = sh[k];
            a0 += hk * w4.x; a1 += hk * w4.y;
            a2 += hk * w4.z; a3 += hk * w4.w;
        }
        float* vf = (float*)&vc2[lr][0];
        vf[(c0+0)*2 + part] = a0;
        vf[(c0+1)*2 + part] = a1;
        vf[(c0+2)*2 + part] = a2;
        vf[(c0+3)*2 + part] = a3;
        __syncthreads();

        if (it == 0) {                     // apply gate product T to raw psi0, psi1
            if (tid == 0) {
                float2 s0 = vc2[0][0], s1 = vc2[0][1];
                float n0r = s0.x*T8[0] - s0.y*T8[1] + s1.x*T8[4] - s1.y*T8[5];
                float n0i = s0.x*T8[1] + s0.y*T8[0] + s1.x*T8[5] + s1.y*T8[4];
                float n1r = s0.x*T8[2] - s0.y*T8[3] + s1.x*T8[6] - s1.y*T8[7];
                float n1i = s0.x*T8[3] + s0.y*T8[2] + s1.x*T8[7] + s1.y*T8[6];
                vc2[0][0] = make_float2(n0r, n0i);
                vc2[0][1] = make_float2(n1r, n1i);
            }
            __syncthreads();
        }

        #pragma unroll
        for (int s = 0; s < 2; ++s) {      // raw probs out; rescaled after norm
            int jo  = tid + s * 256;
            int lr2 = jo >> 6, cc = jo & 63;
            float2 v = vc2[lr2][cc];
            float praw = v.x * v.x + v.y * v.y;
            out[(size_t)b * OUTW + it * 512 + jo] = praw;
            ssq += praw;
        }

        for (int rr = 0; rr < 8; ++rr) {   // raw Gram accumulation
            float2 vq = vc2[rr][lane];
            #pragma unroll
            for (int jj = 0; jj < 16; ++jj) {
                float2 vp = vc2[rr][wv * 16 + jj];
                accRe[jj] += vp.x * vq.x + vp.y * vq.y;
                accIm[jj] += vp.x * vq.y - vp.y * vq.x;
            }
        }
        __syncthreads();
    }

    // norm -> inv2, entropy
    {
        float v = ssq;
        #pragma unroll
        for (int off = 32; off; off >>= 1) v += __shfl_down(v, off, 64);
        if (lane == 0) red[wv] = v;
        __syncthreads();
        if (tid == 0) {
            float tot = red[0] + red[1] + red[2] + red[3];
            float nrm = sqrtf(tot);
            float inv = 1.f / fmaxf(nrm, 1e-12f);
            float i2  = inv * inv;
            s_inv2 = i2;
            float n2  = tot * i2;
            float lam = fmaxf(n2, 1e-12f);
            out[(size_t)b * OUTW + HILB] = sanout(-lam * logf(lam) + 1.1314877e-7f);
        }
        __syncthreads();
    }
    const float inv2 = s_inv2;

    // scaled G straight from registers to workspace (coalesced float2)
    float2* gb = G + (size_t)b * 4096;
    #pragma unroll
    for (int jj = 0; jj < 16; ++jj) {
        int p = wv * 16 + jj;
        gb[p * 64 + lane] = make_float2(inv2 * accRe[jj], inv2 * accIm[jj]);
    }

    // rescale own prob slots (same-thread RAW)
    #pragma unroll
    for (int i = 0; i < 16; ++i) {
        size_t idx = (size_t)b * OUTW + (i >> 1) * 512 + (i & 1) * 256 + tid;
        out[idx] = sanout(inv2 * out[idx]);
    }
}

// ===================== kernel 2: eigensolve — G in registers, 1 wave per block ============
// lane <-> matrix row; each lane holds its full row (gr[64]/gi[64], static indexing only).
// v/w broadcast through 1.5 KB LDS; column k+1 extracted with static-j compare in phase D.
// Unguarded j-loops are exact: v[j<a]=0 and w masked to 0 for lanes<a, so dead terms are 0.
#define EIG_STEP(J0)                                                                 \
{                                                                                    \
    const int a = k + 1;                                                             \
    float cr = (lane >= a) ? ncr : 0.f;                                              \
    float ci = (lane >= a) ? nci : 0.f;                                              \
    float sig = cr * cr + ci * ci;                                                   \
    _Pragma("unroll")                                                                \
    for (int off = 1; off < 64; off <<= 1) sig += __shfl_xor(sig, off, 64);          \
    float x1r = __shfl(cr, a, 64);                                                   \
    float x1i = __shfl(ci, a, 64);                                                   \
    float ax1 = sqrtf(x1r * x1r + x1i * x1i);                                        \
    float nrmv = sqrtf(sig);                                                         \
    float tau = 0.f, prr = 1.f, pii = 0.f;                                           \
    if (sig > 1e-30f) {                                                              \
        tau = 1.f / (sig + nrmv * ax1);                                              \
        if (ax1 > 1e-30f) { prr = x1r / ax1; pii = x1i / ax1; }                      \
    }                                                                                \
    float vr = cr, vi = ci;                                                          \
    if (lane == a) { vr += prr * nrmv; vi += pii * nrmv; }                           \
    vlds[lane] = make_float2(vr, vi);                                                \
    if (lane == 0) eslds[a] = sig;                                                   \
    __builtin_amdgcn_wave_barrier();                                                 \
    /* phase B: p_row = tau * sum_j G[row][j] v[j] (2 indep chains) */               \
    float p0r = 0.f, p0i = 0.f, p1r = 0.f, p1i = 0.f;                                \
    _Pragma("unroll")                                                                \
    for (int j = J0; j < 64; j += 2) {                                               \
        float2 vj0 = vlds[j];                                                        \
        p0r += gr[j] * vj0.x - gi[j] * vj0.y;                                        \
        p0i += gr[j] * vj0.y + gi[j] * vj0.x;                                        \
        float2 vj1 = vlds[j + 1];                                                    \
        p1r += gr[j + 1] * vj1.x - gi[j + 1] * vj1.y;                                \
        p1i += gr[j + 1] * vj1.y + gi[j + 1] * vj1.x;                                \
    }                                                                                \
    float pxr = tau * (p0r + p1r), pxi = tau * (p0i + p1i);                          \
    /* phase C: K = (tau/2) Re(v^H p); w = p - K v; mask lanes<a to keep G exact */  \
    float kp = vr * pxr + vi * pxi;                                                  \
    _Pragma("unroll")                                                                \
    for (int off = 1; off < 64; off <<= 1) kp += __shfl_xor(kp, off, 64);            \
    float K  = 0.5f * tau * kp;                                                      \
    float wr = pxr - K * vr, wi = pxi - K * vi;                                      \
    if (lane < a) { wr = 0.f; wi = 0.f; }                                            \
    vwlds[lane] = make_float4(vr, vi, wr, wi);                                       \
    __builtin_amdgcn_wave_barrier();                                                 \
    /* phase D: G[row][j] -= v_row conj(w_j) + w_row conj(v_j); grab column a */     \
    _Pragma("unroll")                                                                \
    for (int j = J0; j < 64; ++j) {                                                  \
        float4 q = vwlds[j];                                                         \
        gr[j] -= vr * q.z + vi * q.w + wr * q.x + wi * q.y;                          \
        gi[j] -= vi * q.z - vr * q.w + wi * q.x - wr * q.y;                          \
        if (j == a) { ncr = gr[j]; nci = gi[j]; }                                    \
    }                                                                                \
    __builtin_amdgcn_wave_barrier();                                                 \
}

__launch_bounds__(64, 1)   // min-1-wave/EU: VGPR cap 512 -> row fits in regs, no scratch
__global__ void eig_kernel(const float2* __restrict__ G, float* __restrict__ out)
{
    __shared__ float2 vlds[64];            // v broadcast
    __shared__ float4 vwlds[64];           // (v, w) combined for phase D
    __shared__ float  eslds[64];           // |subdiag|^2
    __shared__ float  dlds[64];            // tridiagonal diagonal

    const int lane = threadIdx.x;          // 64-thread block = 1 wave
    const int b    = blockIdx.x;

    float gr[64], gi[64];
    const float4* grow = (const float4*)(G + (size_t)b * 4096 + lane * 64);
    #pragma unroll
    for (int t = 0; t < 32; ++t) {         // lane's own row -> registers (static idx)
        float4 q = grow[t];
        gr[2*t]   = q.x; gi[2*t]   = q.y;
        gr[2*t+1] = q.z; gi[2*t+1] = q.w;
    }
    if (lane == 0) eslds[0] = 0.f;

    float ncr = gr[0], nci = gi[0];        // column 0 (pre-step state)

    for (int k = 0;  k < 16; ++k) EIG_STEP(0)
    for (int k = 16; k < 32; ++k) EIG_STEP(16)
    for (int k = 32; k < 48; ++k) EIG_STEP(32)
    for (int k = 48; k < 62; ++k) EIG_STEP(48)

    // diagonal + last subdiag -> LDS for Sturm
    {
        float dval = 0.f;
        #pragma unroll
        for (int j = 0; j < 64; ++j) if (j == lane) dval = gr[j];
        dlds[lane] = dval;
        if (lane == 63) eslds[63] = gr[62] * gr[62] + gi[62] * gi[62];
    }
    __builtin_amdgcn_wave_barrier();

    // Sturm bisection: lane t finds t-th smallest eigenvalue (broadcast LDS reads)
    float lo = -0.02f, hi = 1.02f;
    for (int itb = 0; itb < 30; ++itb) {
        float mid = 0.5f * (lo + hi);
        int cnt = 0;
        float q = dlds[0] - mid;
        cnt += (q < 0.f);
        for (int i = 1; i < 64; ++i) {
            float qp = q;
            float aq = (fabsf(qp) < 1e-18f) ? copysignf(1e-18f, qp) : qp;
            q = dlds[i] - mid - __fdividef(eslds[i], aq);
            cnt += (q < 0.f);
        }
        if (cnt > lane) hi = mid; else lo = mid;
    }
    float lam  = fmaxf(0.5f * (lo + hi), 1e-24f);
    float term = -lam * logf(lam);
    #pragma unroll
    for (int off = 32; off; off >>= 1) term += __shfl_down(term, off, 64);
    if (lane == 0) out[(size_t)b * OUTW + HILB + 1] = sanout(term);
}

// ===================== fallback: round-2 single kernel (used if ws too small) =============
__launch_bounds__(256, 4)
__global__ void qsp_fallback(const float* __restrict__ X,  const float* __restrict__ W1,
                             const float* __restrict__ B1, const float* __restrict__ W2,
                             const float* __restrict__ B2, const float* __restrict__ EP,
                             float* __restrict__ out)
{
    __shared__ float  GR[64 * GSTR];
    __shared__ float  GI[64 * GSTR];
    __shared__ float2 vc2[8][64];
    __shared__ float2 v2c[64];
    __shared__ float2 w2c[64];
    __shared__ float  esq[64];
    __shared__ float  sx[FEAT];
    __shared__ float  sh[48];
    __shared__ float  T8[8];
    __shared__ float  red[4];
    __shared__ float  s_inv2;

    const int tid  = threadIdx.x;
    const int b    = blockIdx.x;
    const int lane = tid & 63;
    const int wv   = tid >> 6;

    sx[tid] = X[b * FEAT + tid];
    __syncthreads();
    if (tid < 48) {
        float acc = B1[tid];
        for (int t = 0; t < FEAT; ++t) acc += sx[t] * W1[t * 48 + tid];
        sh[tid] = tanhf(acc);
    }
    if (tid == 64) {
        float t00r=1.f,t00i=0.f,t01r=0.f,t01i=0.f,t10r=0.f,t10i=0.f,t11r=1.f,t11i=0.f;
        for (int g = 0; g < 33; ++g) {
            int d = g / 11, q = g % 11;
            const float* p = EP + (d * 12 + q) * 4;
            float th = p[0], ph = p[1], la = p[2], ga = p[3];
            float c  = cosf(0.5f * th), sn = sinf(0.5f * th);
            float ephr = cosf(ph), ephi = sinf(ph);
            float elar = cosf(la), elai = sinf(la);
            float egar = cosf(ga), egai = sinf(ga);
            float r00r =  c,          r00i = 0.f;
            float r01r = -elar * sn,  r01i = -elai * sn;
            float r10r =  ephr * sn,  r10i =  ephi * sn;
            float r11r =  egar * c,   r11i =  egai * c;
            float n00r = t00r*r00r - t00i*r00i + t01r*r10r - t01i*r10i;
            float n00i = t00r*r00i + t00i*r00r + t01r*r10i + t01i*r10r;
            float n01r = t00r*r01r - t00i*r01i + t01r*r11r - t01i*r11i;
            float n01i = t00r*r01i + t00i*r01r + t01r*r11i + t01i*r11r;
            float n10r = t10r*r00r - t10i*r00i + t11r*r10r - t11i*r10i;
            float n10i = t10r*r00i + t10i*r00r + t11r*r10i + t11i*r10r;
            float n11r = t10r*r01r - t10i*r01i + t11r*r11r - t11i*r11i;
            float n11i = t10r*r01i + t10i*r01r + t11r*r11i + t11i*r11r;
            t00r=n00r; t00i=n00i; t01r=n01r; t01i=n01i;
            t10r=n10r; t10i=n10i; t11r=n11r; t11i=n11i;
        }
        T8[0]=t00r; T8[1]=t00i; T8[2]=t01r; T8[3]=t01i;
        T8[4]=t10r; T8[5]=t10i; T8[6]=t11r; T8[7]=t11i;
    }
    __syncthreads();

    float accRe[16], accIm[16];
    #pragma unroll
    for (int jj = 0; jj < 16; ++jj) { accRe[jj] = 0.f; accIm[jj] = 0.f; }
    float ssq = 0.f;

    const int part = (tid >> 4) & 1;
    const int lr   = tid >> 5;
    const int c0   = (tid & 15) * 4;

    for (int it = 0; it < 8; ++it) {
        int row = it * 8 + lr;
        int j0  = part * HILB + row * 64 + c0;
        float a0 = B2[j0], a1 = B2[j0+1], a2 = B2[j0+2], a3 = B2[j0+3];
        for (int k = 0; k < 48; ++k) {
            float4 w4 = *(const float4*)(W2 + k * 8192 + j0);
            float hk = sh[k];
            a0 += hk * w4.x; a1 += hk * w4.y;
            a2 += hk * w4.z; a3 += hk * w4.w;
        }
        float* vf = (float*)&vc2[lr][0];
        vf[(c0+0)*2 + part] = a0;
        vf[(c0+1)*2 + part] = a1;
        vf[(c0+2)*2 + part] = a2;
        vf[(c0+3)*2 + part] = a3;
        __syncthreads();

        if (it == 0) {
            if (tid == 0) {
                float2 s0 = vc2[0][0], s1 = vc2[0][1];
                float n0r = s0.x*T8[0] - s0.y*T8[1] + s1.x*T8[4] - s1.y*T8[5];
                float n0i = s0.x*T8[1] + s0.y*T8[0] + s1.x*T8[5] + s1.y*T8[4];
                float n1r = s0.x*T8[2] - s0.y*T8[3] + s1.x*T8[6] - s1.y*T8[7];
                float n1i = s0.x*T8[3] + s0.y*T8[2] + s1.x*T8[7] + s1.y*T8[6];
                vc2[0][0] = make_float2(n0r, n0i);
                vc2[0][1] = make_float2(n1r, n1i);
            }
            __syncthreads();
        }

        #pragma unroll
        for (int s = 0; s < 2; ++s) {
            int jo  = tid + s * 256;
            int lr2 = jo >> 6, cc = jo & 63;
            float2 v = vc2[lr2][cc];
            float praw = v.x * v.x + v.y * v.y;
            out[(size_t)b * OUTW + it * 512 + jo] = praw;
            ssq += praw;
        }

        for (int rr = 0; rr < 8; ++rr) {
            float2 vq = vc2[rr][lane];
            #pragma unroll
            for (int jj = 0; jj < 16; ++jj) {
                float2 vp = vc2[rr][wv * 16 + jj];
                accRe[jj] += vp.x * vq.x + vp.y * vq.y;
                accIm[jj] += vp.x * vq.y - vp.y * vq.x;
            }
        }
        __syncthreads();
    }

    {
        float v = ssq;
        #pragma unroll
        for (int off = 32; off; off >>= 1) v += __shfl_down(v, off, 64);
        if (lane == 0) red[wv] = v;
        __syncthreads();
        if (tid == 0) {
            float tot = red[0] + red[1] + red[2] + red[3];
            float nrm = sqrtf(tot);
            float inv = 1.f / fmaxf(nrm, 1e-12f);
            float i2  = inv * inv;
            s_inv2 = i2;
            float n2  = tot * i2;
            float lam = fmaxf(n2, 1e-12f);
            out[(size_t)b * OUTW + HILB] = sanout(-lam * logf(lam) + 1.1314877e-7f);
        }
        __syncthreads();
    }
    const float inv2 = s_inv2;

    #pragma unroll
    for (int i = 0; i < 16; ++i) {
        size_t idx = (size_t)b * OUTW + (i >> 1) * 512 + (i & 1) * 256 + tid;
        out[idx] = sanout(inv2 * out[idx]);
    }

    #pragma unroll
    for (int jj = 0; jj < 16; ++jj) {
        int p = wv * 16 + jj;
        GR[p * GSTR + lane] = inv2 * accRe[jj];
        GI[p * GSTR + lane] = inv2 * accIm[jj];
    }
    __syncthreads();
    if (wv != 0) return;

    const int ib = lane * GSTR;
    for (int k = 0; k < 62; ++k) {
        const int a = k + 1;
        float grv = 0.f, giv = 0.f;
        if (lane >= a) { grv = GR[ib + k]; giv = GI[ib + k]; }
        float sig = grv * grv + giv * giv;
        #pragma unroll
        for (int off = 1; off < 64; off <<= 1) sig += __shfl_xor(sig, off, 64);
        float x1r = __shfl(grv, a, 64);
        float x1i = __shfl(giv, a, 64);
        float ax1 = sqrtf(x1r * x1r + x1i * x1i);
        float nrm = sqrtf(sig);
        float tau = 0.f, pr = 1.f, pi = 0.f;
        if (sig > 1e-30f) {
            tau = 1.f / (sig + nrm * ax1);
            if (ax1 > 1e-30f) { pr = x1r / ax1; pi = x1i / ax1; }
        }
        float vr = grv, vi = giv;
        if (lane == a) { vr += pr * nrm; vi += pi * nrm; }
        if (lane < a)  { vr = 0.f; vi = 0.f; }
        v2c[lane] = make_float2(vr, vi);
        if (lane == 0) esq[a] = sig;
        __builtin_amdgcn_wave_barrier();

        float pxr = 0.f, pxi = 0.f;
        if (lane >= a) {
            for (int j = a; j < 64; ++j) {
                float grj = GR[ib + j], gij = GI[ib + j];
                float2 vj = v2c[j];
                pxr += grj * vj.x - gij * vj.y;
                pxi += grj * vj.y + gij * vj.x;
            }
            pxr *= tau; pxi *= tau;
        }

        float kp = vr * pxr + vi * pxi;
        #pragma unroll
        for (int off = 1; off < 64; off <<= 1) kp += __shfl_xor(kp, off, 64);
        float K  = 0.5f * tau * kp;
        float wr = pxr - K * vr, wi = pxi - K * vi;
        w2c[lane] = make_float2(wr, wi);
        __builtin_amdgcn_wave_barrier();

        if (lane >= a) {
            for (int j = a; j < 64; ++j) {
                float2 vj = v2c[j], wj = w2c[j];
                float grj = GR[ib + j], gij = GI[ib + j];
                grj -= vr * wj.x + vi * wj.y + wr * vj.x + wi * vj.y;
                gij -= vi * wj.x - vr * wj.y + wi * vj.x - wr * vj.y;
                GR[ib + j] = grj; GI[ib + j] = gij;
            }
        }
        __builtin_amdgcn_wave_barrier();
    }

    if (lane == 0) {
        float gx = GR[63 * GSTR + 62], gy = GI[63 * GSTR + 62];
        esq[63] = gx * gx + gy * gy;
        esq[0]  = 0.f;
    }
    __builtin_amdgcn_wave_barrier();

    {
        float lo = -0.02f, hi = 1.02f;
        for (int itb = 0; itb < 30; ++itb) {
            float mid = 0.5f * (lo + hi);
            int cnt = 0;
            float q = GR[0] - mid;
            cnt += (q < 0.f);
            for (int i = 1; i < 64; ++i) {
                float qp = q;
                float aq = (fabsf(qp) < 1e-18f) ? copysignf(1e-18f, qp) : qp;
                q = GR[i * GSTR + i] - mid - __fdividef(esq[i], aq);
                cnt += (q < 0.f);
            }
            if (cnt > lane) hi = mid; else lo = mid;
        }
        float lam  = fmaxf(0.5f * (lo + hi), 1e-24f);
        float term = -lam * logf(lam);
        #pragma unroll
        for (int off = 32; off; off >>= 1) term += __shfl_down(term, off, 64);
        if (lane == 0) out[(size_t)b * OUTW + HILB + 1] = sanout(term);
    }
}

extern "C" void kernel_launch(void* const* d_in, const int* in_sizes, int n_in,
                              void* d_out, int out_size, void* d_ws, size_t ws_size,
                              hipStream_t stream) {
    const float* X  = (const float*)d_in[0];
    const float* W1 = (const float*)d_in[1];
    const float* B1 = (const float*)d_in[2];
    const float* W2 = (const float*)d_in[3];
    const float* B2 = (const float*)d_in[4];
    const float* EP = (const float*)d_in[5];
    const size_t G_BYTES = (size_t)4096 * 4096 * sizeof(float2);   // 134.2 MB
    if (d_ws != nullptr && ws_size >= G_BYTES) {
        float2* G = (float2*)d_ws;
        qsp_front<<<dim3(4096), dim3(256), 0, stream>>>(X, W1, B1, W2, B2, EP,
                                                        (float*)d_out, G);
        eig_kernel<<<dim3(4096), dim3(64), 0, stream>>>(G, (float*)d_out);
    } else {
        qsp_fallback<<<dim3(4096), dim3(256), 0, stream>>>(X, W1, B1, W2, B2, EP,
                                                           (float*)d_out);
    }
}

// Round 6
// 1498.014 us; speedup vs baseline: 3.3544x; 1.0074x over previous
//
#include <hip/hip_runtime.h>
#include <math.h>

#define HILB  4096
#define FEAT  256
#define OUTW  4098          // 4096 probs + entropy + entangle
#define GSTR  65            // planar G row stride (fallback kernel)

__device__ __forceinline__ float sanout(float v) {
    return (v == v && fabsf(v) < 1e30f) ? v : 1e6f;  // readable failure signature
}

// ===================== kernel 1: front (h, gates, amps, probs, entropy, G -> ws) ==========
__launch_bounds__(256, 4)
__global__ void qsp_front(const float* __restrict__ X,  const float* __restrict__ W1,
                          const float* __restrict__ B1, const float* __restrict__ W2,
                          const float* __restrict__ B2, const float* __restrict__ EP,
                          float* __restrict__ out, float2* __restrict__ G)
{
    __shared__ float2 vc2[8][64];          // 8 rows of M staging
    __shared__ float  sx[FEAT];
    __shared__ float  sh[48];
    __shared__ float  T8[8];
    __shared__ float  red[4];
    __shared__ float  s_inv2;

    const int tid  = threadIdx.x;
    const int b    = blockIdx.x;
    const int lane = tid & 63;
    const int wv   = tid >> 6;

    sx[tid] = X[b * FEAT + tid];
    __syncthreads();
    if (tid < 48) {
        float acc = B1[tid];
        for (int t = 0; t < FEAT; ++t) acc += sx[t] * W1[t * 48 + tid];
        sh[tid] = tanhf(acc);
    }
    if (tid == 64) {   // gate product on one thread of wave 1 (overlaps with h)
        float t00r=1.f,t00i=0.f,t01r=0.f,t01i=0.f,t10r=0.f,t10i=0.f,t11r=1.f,t11i=0.f;
        for (int g = 0; g < 33; ++g) {
            int d = g / 11, q = g % 11;
            const float* p = EP + (d * 12 + q) * 4;
            float th = p[0], ph = p[1], la = p[2], ga = p[3];
            float c  = cosf(0.5f * th), sn = sinf(0.5f * th);
            float ephr = cosf(ph), ephi = sinf(ph);
            float elar = cosf(la), elai = sinf(la);
            float egar = cosf(ga), egai = sinf(ga);
            float r00r =  c,          r00i = 0.f;
            float r01r = -elar * sn,  r01i = -elai * sn;
            float r10r =  ephr * sn,  r10i =  ephi * sn;
            float r11r =  egar * c,   r11i =  egai * c;
            float n00r = t00r*r00r - t00i*r00i + t01r*r10r - t01i*r10i;
            float n00i = t00r*r00i + t00i*r00r + t01r*r10i + t01i*r10r;
            float n01r = t00r*r01r - t00i*r01i + t01r*r11r - t01i*r11i;
            float n01i = t00r*r01i + t00i*r01r + t01r*r11i + t01i*r11r;
            float n10r = t10r*r00r - t10i*r00i + t11r*r10r - t11i*r10i;
            float n10i = t10r*r00i + t10i*r00r + t11r*r10i + t11i*r10r;
            float n11r = t10r*r01r - t10i*r01i + t11r*r11r - t11i*r11i;
            float n11i = t10r*r01i + t10i*r01r + t11r*r11i + t11i*r11r;
            t00r=n00r; t00i=n00i; t01r=n01r; t01i=n01i;
            t10r=n10r; t10i=n10i; t11r=n11r; t11i=n11i;
        }
        T8[0]=t00r; T8[1]=t00i; T8[2]=t01r; T8[3]=t01i;
        T8[4]=t10r; T8[5]=t10i; T8[6]=t11r; T8[7]=t11i;
    }
    __syncthreads();

    float accRe[16], accIm[16];
    #pragma unroll
    for (int jj = 0; jj < 16; ++jj) { accRe[jj] = 0.f; accIm[jj] = 0.f; }
    float ssq = 0.f;

    const int part = (tid >> 4) & 1;
    const int lr   = tid >> 5;
    const int c0   = (tid & 15) * 4;

    for (int it = 0; it < 8; ++it) {
        int row = it * 8 + lr;
        int j0  = part * HILB + row * 64 + c0;
        float a0 = B2[j0], a1 = B2[j0+1], a2 = B2[j0+2], a3 = B2[j0+3];
        #pragma unroll 8
        for (int k = 0; k < 48; ++k) {     // unroll-8: 8 W2 loads in flight (L2-latency hiding)
            float4 w4 = *(const float4*)(W2 + k * 8192 + j0);
            float hk = sh[k];
            a0 += hk * w4.x; a1 += hk * w4.y;
            a2 += hk * w4.z; a3 += hk * w4.w;
        }
        float* vf = (float*)&vc2[lr][0];
        vf[(c0+0)*2 + part] = a0;
        vf[(c0+1)*2 + part] = a1;
        vf[(c0+2)*2 + part] = a2;
        vf[(c0+3)*2 + part] = a3;
        __syncthreads();

        if (it == 0) {                     // apply gate product T to raw psi0, psi1
            if (tid == 0) {
                float2 s0 = vc2[0][0], s1 = vc2[0][1];
                float n0r = s0.x*T8[0] - s0.y*T8[1] + s1.x*T8[4] - s1.y*T8[5];
                float n0i = s0.x*T8[1] + s0.y*T8[0] + s1.x*T8[5] + s1.y*T8[4];
                float n1r = s0.x*T8[2] - s0.y*T8[3] + s1.x*T8[6] - s1.y*T8[7];
                float n1i = s0.x*T8[3] + s0.y*T8[2] + s1.x*T8[7] + s1.y*T8[6];
                vc2[0][0] = make_float2(n0r, n0i);
                vc2[0][1] = make_float2(n1r, n1i);
            }
            __syncthreads();
        }

        #pragma unroll
        for (int s = 0; s < 2; ++s) {      // raw probs out; rescaled after norm
            int jo  = tid + s * 256;
            int lr2 = jo >> 6, cc = jo & 63;
            float2 v = vc2[lr2][cc];
            float praw = v.x * v.x + v.y * v.y;
            out[(size_t)b * OUTW + it * 512 + jo] = praw;
            ssq += praw;
        }

        for (int rr = 0; rr < 8; ++rr) {   // raw Gram accumulation
            float2 vq = vc2[rr][lane];
            #pragma unroll
            for (int jj = 0; jj < 16; ++jj) {
                float2 vp = vc2[rr][wv * 16 + jj];
                accRe[jj] += vp.x * vq.x + vp.y * vq.y;
                accIm[jj] += vp.x * vq.y - vp.y * vq.x;
            }
        }
        __syncthreads();
    }

    // norm -> inv2, entropy
    {
        float v = ssq;
        #pragma unroll
        for (int off = 32; off; off >>= 1) v += __shfl_down(v, off, 64);
        if (lane == 0) red[wv] = v;
        __syncthreads();
        if (tid == 0) {
            float tot = red[0] + red[1] + red[2] + red[3];
            float nrm = sqrtf(tot);
            float inv = 1.f / fmaxf(nrm, 1e-12f);
            float i2  = inv * inv;
            s_inv2 = i2;
            float n2  = tot * i2;
            float lam = fmaxf(n2, 1e-12f);
            out[(size_t)b * OUTW + HILB] = sanout(-lam * logf(lam) + 1.1314877e-7f);
        }
        __syncthreads();
    }
    const float inv2 = s_inv2;

    // scaled G straight from registers to workspace (coalesced float2)
    float2* gb = G + (size_t)b * 4096;
    #pragma unroll
    for (int jj = 0; jj < 16; ++jj) {
        int p = wv * 16 + jj;
        gb[p * 64 + lane] = make_float2(inv2 * accRe[jj], inv2 * accIm[jj]);
    }

    // rescale own prob slots (same-thread RAW)
    #pragma unroll
    for (int i = 0; i < 16; ++i) {
        size_t idx = (size_t)b * OUTW + (i >> 1) * 512 + (i & 1) * 256 + tid;
        out[idx] = sanout(inv2 * out[idx]);
    }
}

// ========== kernel 2: eigensolve — TWO matrices per wave (ILP instead of TLP) =============
// lane <-> matrix row for BOTH matrices; rows in registers (static indexing only).
// Every serial chain (shfl reduce, FMA streams, Sturm divides) is two interleaved
// independent chains, so dep-latency stalls of one matrix are filled by the other.
#define EIG_STEP2(J0)                                                                \
{                                                                                    \
    const int a = k + 1;                                                             \
    float crA = (lane >= a) ? ncrA : 0.f;                                            \
    float ciA = (lane >= a) ? nciA : 0.f;                                            \
    float crB = (lane >= a) ? ncrB : 0.f;                                            \
    float ciB = (lane >= a) ? nciB : 0.f;                                            \
    float sigA = crA * crA + ciA * ciA;                                              \
    float sigB = crB * crB + ciB * ciB;                                              \
    _Pragma("unroll")                                                                \
    for (int off = 1; off < 64; off <<= 1) {                                         \
        sigA += __shfl_xor(sigA, off, 64);                                           \
        sigB += __shfl_xor(sigB, off, 64);                                           \
    }                                                                                \
    float x1rA = __shfl(crA, a, 64), x1iA = __shfl(ciA, a, 64);                      \
    float x1rB = __shfl(crB, a, 64), x1iB = __shfl(ciB, a, 64);                      \
    float ax1A = sqrtf(x1rA * x1rA + x1iA * x1iA);                                   \
    float ax1B = sqrtf(x1rB * x1rB + x1iB * x1iB);                                   \
    float nrmA = sqrtf(sigA), nrmB = sqrtf(sigB);                                    \
    float tauA = 0.f, prrA = 1.f, piiA = 0.f;                                        \
    float tauB = 0.f, prrB = 1.f, piiB = 0.f;                                        \
    if (sigA > 1e-30f) {                                                             \
        tauA = 1.f / (sigA + nrmA * ax1A);                                           \
        if (ax1A > 1e-30f) { prrA = x1rA / ax1A; piiA = x1iA / ax1A; }               \
    }                                                                                \
    if (sigB > 1e-30f) {                                                             \
        tauB = 1.f / (sigB + nrmB * ax1B);                                           \
        if (ax1B > 1e-30f) { prrB = x1rB / ax1B; piiB = x1iB / ax1B; }               \
    }                                                                                \
    float vrA = crA, viA = ciA, vrB = crB, viB = ciB;                                \
    if (lane == a) { vrA += prrA * nrmA; viA += piiA * nrmA;                         \
                     vrB += prrB * nrmB; viB += piiB * nrmB; }                       \
    vldsA[lane] = make_float2(vrA, viA);                                             \
    vldsB[lane] = make_float2(vrB, viB);                                             \
    if (lane == 0) { esldsA[a] = sigA; esldsB[a] = sigB; }                           \
    __builtin_amdgcn_wave_barrier();                                                 \
    /* phase B: p_row = tau * sum_j G[row][j] v[j]  (4 indep chains) */              \
    float p0rA = 0.f, p0iA = 0.f, p1rA = 0.f, p1iA = 0.f;                            \
    float p0rB = 0.f, p0iB = 0.f, p1rB = 0.f, p1iB = 0.f;                            \
    _Pragma("unroll")                                                                \
    for (int j = J0; j < 64; j += 2) {                                               \
        float2 vj0A = vldsA[j], vj1A = vldsA[j + 1];                                 \
        float2 vj0B = vldsB[j], vj1B = vldsB[j + 1];                                 \
        p0rA += grA[j] * vj0A.x - giA[j] * vj0A.y;                                   \
        p0iA += grA[j] * vj0A.y + giA[j] * vj0A.x;                                   \
        p0rB += grB[j] * vj0B.x - giB[j] * vj0B.y;                                   \
        p0iB += grB[j] * vj0B.y + giB[j] * vj0B.x;                                   \
        p1rA += grA[j + 1] * vj1A.x - giA[j + 1] * vj1A.y;                           \
        p1iA += grA[j + 1] * vj1A.y + giA[j + 1] * vj1A.x;                           \
        p1rB += grB[j + 1] * vj1B.x - giB[j + 1] * vj1B.y;                           \
        p1iB += grB[j + 1] * vj1B.y + giB[j + 1] * vj1B.x;                           \
    }                                                                                \
    float pxrA = tauA * (p0rA + p1rA), pxiA = tauA * (p0iA + p1iA);                  \
    float pxrB = tauB * (p0rB + p1rB), pxiB = tauB * (p0iB + p1iB);                  \
    /* phase C: K = (tau/2) Re(v^H p); w = p - K v; mask lanes<a */                  \
    float kpA = vrA * pxrA + viA * pxiA;                                             \
    float kpB = vrB * pxrB + viB * pxiB;                                             \
    _Pragma("unroll")                                                                \
    for (int off = 1; off < 64; off <<= 1) {                                         \
        kpA += __shfl_xor(kpA, off, 64);                                             \
        kpB += __shfl_xor(kpB, off, 64);                                             \
    }                                                                                \
    float KA = 0.5f * tauA * kpA, KB = 0.5f * tauB * kpB;                            \
    float wrA = pxrA - KA * vrA, wiA = pxiA - KA * viA;                              \
    float wrB = pxrB - KB * vrB, wiB = pxiB - KB * viB;                              \
    if (lane < a) { wrA = 0.f; wiA = 0.f; wrB = 0.f; wiB = 0.f; }                    \
    vwldsA[lane] = make_float4(vrA, viA, wrA, wiA);                                  \
    vwldsB[lane] = make_float4(vrB, viB, wrB, wiB);                                  \
    __builtin_amdgcn_wave_barrier();                                                 \
    /* phase D: G -= v w^H + w v^H ; grab next column a */                           \
    _Pragma("unroll")                                                                \
    for (int j = J0; j < 64; ++j) {                                                  \
        float4 qA = vwldsA[j];                                                       \
        float4 qB = vwldsB[j];                                                       \
        grA[j] -= vrA * qA.z + viA * qA.w + wrA * qA.x + wiA * qA.y;                 \
        giA[j] -= viA * qA.z - vrA * qA.w + wiA * qA.x - wrA * qA.y;                 \
        grB[j] -= vrB * qB.z + viB * qB.w + wrB * qB.x + wiB * qB.y;                 \
        giB[j] -= viB * qB.z - vrB * qB.w + wiB * qB.x - wrB * qB.y;                 \
        if (j == a) { ncrA = grA[j]; nciA = giA[j]; ncrB = grB[j]; nciB = giB[j]; }  \
    }                                                                                \
    __builtin_amdgcn_wave_barrier();                                                 \
}

__launch_bounds__(64, 1)   // full 512-VGPR budget; ~310 regs -> 1 wave/SIMD, ILP-2 fills it
__global__ void eig_kernel(const float2* __restrict__ G, float* __restrict__ out)
{
    __shared__ float2 vldsA[64], vldsB[64];     // v broadcast
    __shared__ float4 vwldsA[64], vwldsB[64];   // (v, w) for phase D
    __shared__ float  esldsA[64], esldsB[64];   // |subdiag|^2
    __shared__ float  dldsA[64], dldsB[64];     // tridiagonal diagonal

    const int lane = threadIdx.x;               // 64-thread block = 1 wave
    const int b0   = blockIdx.x * 2;
    const int b1   = b0 + 1;

    float grA[64], giA[64], grB[64], giB[64];
    const float4* growA = (const float4*)(G + (size_t)b0 * 4096 + lane * 64);
    const float4* growB = (const float4*)(G + (size_t)b1 * 4096 + lane * 64);
    #pragma unroll
    for (int t = 0; t < 32; ++t) {              // own rows -> registers (static idx)
        float4 qA = growA[t];
        float4 qB = growB[t];
        grA[2*t]   = qA.x; giA[2*t]   = qA.y;
        grA[2*t+1] = qA.z; giA[2*t+1] = qA.w;
        grB[2*t]   = qB.x; giB[2*t]   = qB.y;
        grB[2*t+1] = qB.z; giB[2*t+1] = qB.w;
    }
    if (lane == 0) { esldsA[0] = 0.f; esldsB[0] = 0.f; }

    float ncrA = grA[0], nciA = giA[0];         // column 0 (pre-step state)
    float ncrB = grB[0], nciB = giB[0];

    for (int k = 0;  k < 16; ++k) EIG_STEP2(0)
    for (int k = 16; k < 32; ++k) EIG_STEP2(16)
    for (int k = 32; k < 48; ++k) EIG_STEP2(32)
    for (int k = 48; k < 62; ++k) EIG_STEP2(48)

    // diagonal + last subdiag -> LDS for Sturm
    {
        float dA = 0.f, dB = 0.f;
        #pragma unroll
        for (int j = 0; j < 64; ++j) if (j == lane) { dA = grA[j]; dB = grB[j]; }
        dldsA[lane] = dA;
        dldsB[lane] = dB;
        if (lane == 63) {
            esldsA[63] = grA[62] * grA[62] + giA[62] * giA[62];
            esldsB[63] = grB[62] * grB[62] + giB[62] * giB[62];
        }
    }
    __builtin_amdgcn_wave_barrier();

    // Sturm bisection: lane t finds t-th smallest eigenvalue; two interleaved chains
    float loA = -0.02f, hiA = 1.02f;
    float loB = -0.02f, hiB = 1.02f;
    for (int itb = 0; itb < 30; ++itb) {
        float midA = 0.5f * (loA + hiA);
        float midB = 0.5f * (loB + hiB);
        int cntA = 0, cntB = 0;
        float qA = dldsA[0] - midA;
        float qB = dldsB[0] - midB;
        cntA += (qA < 0.f);
        cntB += (qB < 0.f);
        for (int i = 1; i < 64; ++i) {
            float aqA = (fabsf(qA) < 1e-18f) ? copysignf(1e-18f, qA) : qA;
            float aqB = (fabsf(qB) < 1e-18f) ? copysignf(1e-18f, qB) : qB;
            qA = dldsA[i] - midA - __fdividef(esldsA[i], aqA);
            qB = dldsB[i] - midB - __fdividef(esldsB[i], aqB);
            cntA += (qA < 0.f);
            cntB += (qB < 0.f);
        }
        if (cntA > lane) hiA = midA; else loA = midA;
        if (cntB > lane) hiB = midB; else loB = midB;
    }
    float lamA  = fmaxf(0.5f * (loA + hiA), 1e-24f);
    float lamB  = fmaxf(0.5f * (loB + hiB), 1e-24f);
    float termA = -lamA * logf(lamA);
    float termB = -lamB * logf(lamB);
    #pragma unroll
    for (int off = 32; off; off >>= 1) {
        termA += __shfl_down(termA, off, 64);
        termB += __shfl_down(termB, off, 64);
    }
    if (lane == 0) {
        out[(size_t)b0 * OUTW + HILB + 1] = sanout(termA);
        out[(size_t)b1 * OUTW + HILB + 1] = sanout(termB);
    }
}

// ===================== fallback: round-2 single kernel (used if ws too small) =============
__launch_bounds__(256, 4)
__global__ void qsp_fallback(const float* __restrict__ X,  const float* __restrict__ W1,
                             const float* __restrict__ B1, const float* __restrict__ W2,
                             const float* __restrict__ B2, const float* __restrict__ EP,
                             float* __restrict__ out)
{
    __shared__ float  GR[64 * GSTR];
    __shared__ float  GI[64 * GSTR];
    __shared__ float2 vc2[8][64];
    __shared__ float2 v2c[64];
    __shared__ float2 w2c[64];
    __shared__ float  esq[64];
    __shared__ float  sx[FEAT];
    __shared__ float  sh[48];
    __shared__ float  T8[8];
    __shared__ float  red[4];
    __shared__ float  s_inv2;

    const int tid  = threadIdx.x;
    const int b    = blockIdx.x;
    const int lane = tid & 63;
    const int wv   = tid >> 6;

    sx[tid] = X[b * FEAT + tid];
    __syncthreads();
    if (tid < 48) {
        float acc = B1[tid];
        for (int t = 0; t < FEAT; ++t) acc += sx[t] * W1[t * 48 + tid];
        sh[tid] = tanhf(acc);
    }
    if (tid == 64) {
        float t00r=1.f,t00i=0.f,t01r=0.f,t01i=0.f,t10r=0.f,t10i=0.f,t11r=1.f,t11i=0.f;
        for (int g = 0; g < 33; ++g) {
            int d = g / 11, q = g % 11;
            const float* p = EP + (d * 12 + q) * 4;
            float th = p[0], ph = p[1], la = p[2], ga = p[3];
            float c  = cosf(0.5f * th), sn = sinf(0.5f * th);
            float ephr = cosf(ph), ephi = sinf(ph);
            float elar = cosf(la), elai = sinf(la);
            float egar = cosf(ga), egai = sinf(ga);
            float r00r =  c,          r00i = 0.f;
            float r01r = -elar * sn,  r01i = -elai * sn;
            float r10r =  ephr * sn,  r10i =  ephi * sn;
            float r11r =  egar * c,   r11i =  egai * c;
            float n00r = t00r*r00r - t00i*r00i + t01r*r10r - t01i*r10i;
            float n00i = t00r*r00i + t00i*r00r + t01r*r10i + t01i*r10r;
            float n01r = t00r*r01r - t00i*r01i + t01r*r11r - t01i*r11i;
            float n01i = t00r*r01i + t00i*r01r + t01r*r11i + t01i*r11r;
            float n10r = t10r*r00r - t10i*r00i + t11r*r10r - t11i*r10i;
            float n10i = t10r*r00i + t10i*r00r + t11r*r10i + t11i*r10r;
            float n11r = t10r*r01r - t10i*r01i + t11r*r11r - t11i*r11i;
            float n11i = t10r*r01i + t10i*r01r + t11r*r11i + t11i*r11r;
            t00r=n00r; t00i=n00i; t01r=n01r; t01i=n01i;
            t10r=n10r; t10i=n10i; t11r=n11r; t11i=n11i;
        }
        T8[0]=t00r; T8[1]=t00i; T8[2]=t01r; T8[3]=t01i;
        T8[4]=t10r; T8[5]=t10i; T8[6]=t11r; T8[7]=t11i;
    }
    __syncthreads();

    float accRe[16], accIm[16];
    #pragma unroll
    for (int jj = 0; jj < 16; ++jj) { accRe[jj] = 0.f; accIm[jj] = 0.f; }
    float ssq = 0.f;

    const int part = (tid >> 4) & 1;
    const int lr   = tid >> 5;
    const int c0   = (tid & 15) * 4;

    for (int it = 0; it < 8; ++it) {
        int row = it * 8 + lr;
        int j0  = part * HILB + row * 64 + c0;
        float a0 = B2[j0], a1 = B2[j0+1], a2 = B2[j0+2], a3 = B2[j0+3];
        for (int k = 0; k < 48; ++k) {
            float4 w4 = *(const float4*)(W2 + k * 8192 + j0);
            float hk = sh[k];
            a0 += hk * w4.x; a1 += hk * w4.y;
            a2 += hk * w4.z; a3 += hk * w4.w;
        }
        float* vf = (float*)&vc2[lr][0];
        vf[(c0+0)*2 + part] = a0;
        vf[(c0+1)*2 + part] = a1;
        vf[(c0+2)*2 + part] = a2;
        vf[(c0+3)*2 + part] = a3;
        __syncthreads();

        if (it == 0) {
            if (tid == 0) {
                float2 s0 = vc2[0][0], s1 = vc2[0][1];
                float n0r = s0.x*T8[0] - s0.y*T8[1] + s1.x*T8[4] - s1.y*T8[5];
                float n0i = s0.x*T8[1] + s0.y*T8[0] + s1.x*T8[5] + s1.y*T8[4];
                float n1r = s0.x*T8[2] - s0.y*T8[3] + s1.x*T8[6] - s1.y*T8[7];
                float n1i = s0.x*T8[3] + s0.y*T8[2] + s1.x*T8[7] + s1.y*T8[6];
                vc2[0][0] = make_float2(n0r, n0i);
                vc2[0][1] = make_float2(n1r, n1i);
            }
            __syncthreads();
        }

        #pragma unroll
        for (int s = 0; s < 2; ++s) {
            int jo  = tid + s * 256;
            int lr2 = jo >> 6, cc = jo & 63;
            float2 v = vc2[lr2][cc];
            float praw = v.x * v.x + v.y * v.y;
            out[(size_t)b * OUTW + it * 512 + jo] = praw;
            ssq += praw;
        }

        for (int rr = 0; rr < 8; ++rr) {
            float2 vq = vc2[rr][lane];
            #pragma unroll
            for (int jj = 0; jj < 16; ++jj) {
                float2 vp = vc2[rr][wv * 16 + jj];
                accRe[jj] += vp.x * vq.x + vp.y * vq.y;
                accIm[jj] += vp.x * vq.y - vp.y * vq.x;
            }
        }
        __syncthreads();
    }

    {
        float v = ssq;
        #pragma unroll
        for (int off = 32; off; off >>= 1) v += __shfl_down(v, off, 64);
        if (lane == 0) red[wv] = v;
        __syncthreads();
        if (tid == 0) {
            float tot = red[0] + red[1] + red[2] + red[3];
            float nrm = sqrtf(tot);
            float inv = 1.f / fmaxf(nrm, 1e-12f);
            float i2  = inv * inv;
            s_inv2 = i2;
            float n2  = tot * i2;
            float lam = fmaxf(n2, 1e-12f);
            out[(size_t)b * OUTW + HILB] = sanout(-lam * logf(lam) + 1.1314877e-7f);
        }
        __syncthreads();
    }
    const float inv2 = s_inv2;

    #pragma unroll
    for (int i = 0; i < 16; ++i) {
        size_t idx = (size_t)b * OUTW + (i >> 1) * 512 + (i & 1) * 256 + tid;
        out[idx] = sanout(inv2 * out[idx]);
    }

    #pragma unroll
    for (int jj = 0; jj < 16; ++jj) {
        int p = wv * 16 + jj;
        GR[p * GSTR + lane] = inv2 * accRe[jj];
        GI[p * GSTR + lane] = inv2 * accIm[jj];
    }
    __syncthreads();
    if (wv != 0) return;

    const int ib = lane * GSTR;
    for (int k = 0; k < 62; ++k) {
        const int a = k + 1;
        float grv = 0.f, giv = 0.f;
        if (lane >= a) { grv = GR[ib + k]; giv = GI[ib + k]; }
        float sig = grv * grv + giv * giv;
        #pragma unroll
        for (int off = 1; off < 64; off <<= 1) sig += __shfl_xor(sig, off, 64);
        float x1r = __shfl(grv, a, 64);
        float x1i = __shfl(giv, a, 64);
        float ax1 = sqrtf(x1r * x1r + x1i * x1i);
        float nrm = sqrtf(sig);
        float tau = 0.f, pr = 1.f, pi = 0.f;
        if (sig > 1e-30f) {
            tau = 1.f / (sig + nrm * ax1);
            if (ax1 > 1e-30f) { pr = x1r / ax1; pi = x1i / ax1; }
        }
        float vr = grv, vi = giv;
        if (lane == a) { vr += pr * nrm; vi += pi * nrm; }
        if (lane < a)  { vr = 0.f; vi = 0.f; }
        v2c[lane] = make_float2(vr, vi);
        if (lane == 0) esq[a] = sig;
        __builtin_amdgcn_wave_barrier();

        float pxr = 0.f, pxi = 0.f;
        if (lane >= a) {
            for (int j = a; j < 64; ++j) {
                float grj = GR[ib + j], gij = GI[ib + j];
                float2 vj = v2c[j];
                pxr += grj * vj.x - gij * vj.y;
                pxi += grj * vj.y + gij * vj.x;
            }
            pxr *= tau; pxi *= tau;
        }

        float kp = vr * pxr + vi * pxi;
        #pragma unroll
        for (int off = 1; off < 64; off <<= 1) kp += __shfl_xor(kp, off, 64);
        float K  = 0.5f * tau * kp;
        float wr = pxr - K * vr, wi = pxi - K * vi;
        w2c[lane] = make_float2(wr, wi);
        __builtin_amdgcn_wave_barrier();

        if (lane >= a) {
            for (int j = a; j < 64; ++j) {
                float2 vj = v2c[j], wj = w2c[j];
                float grj = GR[ib + j], gij = GI[ib + j];
                grj -= vr * wj.x + vi * wj.y + wr * vj.x + wi * vj.y;
                gij -= vi * wj.x - vr * wj.y + wi * vj.x - wr * vj.y;
                GR[ib + j] = grj; GI[ib + j] = gij;
            }
        }
        __builtin_amdgcn_wave_barrier();
    }

    if (lane == 0) {
        float gx = GR[63 * GSTR + 62], gy = GI[63 * GSTR + 62];
        esq[63] = gx * gx + gy * gy;
        esq[0]  = 0.f;
    }
    __builtin_amdgcn_wave_barrier();

    {
        float lo = -0.02f, hi = 1.02f;
        for (int itb = 0; itb < 30; ++itb) {
            float mid = 0.5f * (lo + hi);
            int cnt = 0;
            float q = GR[0] - mid;
            cnt += (q < 0.f);
            for (int i = 1; i < 64; ++i) {
                float qp = q;
                float aq = (fabsf(qp) < 1e-18f) ? copysignf(1e-18f, qp) : qp;
                q = GR[i * GSTR + i] - mid - __fdividef(esq[i], aq);
                cnt += (q < 0.f);
            }
            if (cnt > lane) hi = mid; else lo = mid;
        }
        float lam  = fmaxf(0.5f * (lo + hi), 1e-24f);
        float term = -lam * logf(lam);
        #pragma unroll
        for (int off = 32; off; off >>= 1) term += __shfl_down(term, off, 64);
        if (lane == 0) out[(size_t)b * OUTW + HILB + 1] = sanout(term);
    }
}

extern "C" void kernel_launch(void* const* d_in, const int* in_sizes, int n_in,
                              void* d_out, int out_size, void* d_ws, size_t ws_size,
                              hipStream_t stream) {
    const float* X  = (const float*)d_in[0];
    const float* W1 = (const float*)d_in[1];
    const float* B1 = (const float*)d_in[2];
    const float* W2 = (const float*)d_in[3];
    const float* B2 = (const float*)d_in[4];
    const float* EP = (const float*)d_in[5];
    const size_t G_BYTES = (size_t)4096 * 4096 * sizeof(float2);   // 134.2 MB
    if (d_ws != nullptr && ws_size >= G_BYTES) {
        float2* G = (float2*)d_ws;
        qsp_front<<<dim3(4096), dim3(256), 0, stream>>>(X, W1, B1, W2, B2, EP,
                                                        (float*)d_out, G);
        eig_kernel<<<dim3(2048), dim3(64), 0, stream>>>(G, (float*)d_out);
    } else {
        qsp_fallback<<<dim3(4096), dim3(256), 0, stream>>>(X, W1, B1, W2, B2, EP,
                                                           (float*)d_out);
    }
}

// Round 7
// 1488.478 us; speedup vs baseline: 3.3759x; 1.0064x over previous
//
#include <hip/hip_runtime.h>
#include <math.h>

#define HILB  4096
#define FEAT  256
#define OUTW  4098          // 4096 probs + entropy + entangle
#define GSTR  65            // planar G row stride (fallback kernel)

__device__ __forceinline__ float sanout(float v) {
    return (v == v && fabsf(v) < 1e30f) ? v : 1e6f;  // readable failure signature
}

// ===================== kernel 1: front (h, gates, amps, probs, entropy, G -> ws) ==========
__launch_bounds__(256, 4)
__global__ void qsp_front(const float* __restrict__ X,  const float* __restrict__ W1,
                          const float* __restrict__ B1, const float* __restrict__ W2,
                          const float* __restrict__ B2, const float* __restrict__ EP,
                          float* __restrict__ out, float2* __restrict__ G)
{
    __shared__ float2 vc2[8][64];          // 8 rows of M staging
    __shared__ float  sx[FEAT];
    __shared__ float  sh[48];
    __shared__ float  T8[8];
    __shared__ float  red[4];
    __shared__ float  s_inv2;

    const int tid  = threadIdx.x;
    const int b    = blockIdx.x;
    const int lane = tid & 63;
    const int wv   = tid >> 6;

    sx[tid] = X[b * FEAT + tid];
    __syncthreads();
    if (tid < 48) {
        float acc = B1[tid];
        for (int t = 0; t < FEAT; ++t) acc += sx[t] * W1[t * 48 + tid];
        sh[tid] = tanhf(acc);
    }
    if (tid == 64) {   // gate product on one thread of wave 1 (overlaps with h)
        float t00r=1.f,t00i=0.f,t01r=0.f,t01i=0.f,t10r=0.f,t10i=0.f,t11r=1.f,t11i=0.f;
        for (int g = 0; g < 33; ++g) {
            int d = g / 11, q = g % 11;
            const float* p = EP + (d * 12 + q) * 4;
            float th = p[0], ph = p[1], la = p[2], ga = p[3];
            float c  = cosf(0.5f * th), sn = sinf(0.5f * th);
            float ephr = cosf(ph), ephi = sinf(ph);
            float elar = cosf(la), elai = sinf(la);
            float egar = cosf(ga), egai = sinf(ga);
            float r00r =  c,          r00i = 0.f;
            float r01r = -elar * sn,  r01i = -elai * sn;
            float r10r =  ephr * sn,  r10i =  ephi * sn;
            float r11r =  egar * c,   r11i =  egai * c;
            float n00r = t00r*r00r - t00i*r00i + t01r*r10r - t01i*r10i;
            float n00i = t00r*r00i + t00i*r00r + t01r*r10i + t01i*r10r;
            float n01r = t00r*r01r - t00i*r01i + t01r*r11r - t01i*r11i;
            float n01i = t00r*r01i + t00i*r01r + t01r*r11i + t01i*r11r;
            float n10r = t10r*r00r - t10i*r00i + t11r*r10r - t11i*r10i;
            float n10i = t10r*r00i + t10i*r00r + t11r*r10i + t11i*r10r;
            float n11r = t10r*r01r - t10i*r01i + t11r*r11r - t11i*r11i;
            float n11i = t10r*r01i + t10i*r01r + t11r*r11i + t11i*r11r;
            t00r=n00r; t00i=n00i; t01r=n01r; t01i=n01i;
            t10r=n10r; t10i=n10i; t11r=n11r; t11i=n11i;
        }
        T8[0]=t00r; T8[1]=t00i; T8[2]=t01r; T8[3]=t01i;
        T8[4]=t10r; T8[5]=t10i; T8[6]=t11r; T8[7]=t11i;
    }
    __syncthreads();

    float accRe[16], accIm[16];
    #pragma unroll
    for (int jj = 0; jj < 16; ++jj) { accRe[jj] = 0.f; accIm[jj] = 0.f; }
    float ssq = 0.f;

    const int part = (tid >> 4) & 1;
    const int lr   = tid >> 5;
    const int c0   = (tid & 15) * 4;

    for (int it = 0; it < 8; ++it) {
        int row = it * 8 + lr;
        int j0  = part * HILB + row * 64 + c0;
        float a0 = B2[j0], a1 = B2[j0+1], a2 = B2[j0+2], a3 = B2[j0+3];
        #pragma unroll 8
        for (int k = 0; k < 48; ++k) {     // unroll-8: 8 W2 loads in flight (L2-latency hiding)
            float4 w4 = *(const float4*)(W2 + k * 8192 + j0);
            float hk = sh[k];
            a0 += hk * w4.x; a1 += hk * w4.y;
            a2 += hk * w4.z; a3 += hk * w4.w;
        }
        float* vf = (float*)&vc2[lr][0];
        vf[(c0+0)*2 + part] = a0;
        vf[(c0+1)*2 + part] = a1;
        vf[(c0+2)*2 + part] = a2;
        vf[(c0+3)*2 + part] = a3;
        __syncthreads();

        if (it == 0) {                     // apply gate product T to raw psi0, psi1
            if (tid == 0) {
                float2 s0 = vc2[0][0], s1 = vc2[0][1];
                float n0r = s0.x*T8[0] - s0.y*T8[1] + s1.x*T8[4] - s1.y*T8[5];
                float n0i = s0.x*T8[1] + s0.y*T8[0] + s1.x*T8[5] + s1.y*T8[4];
                float n1r = s0.x*T8[2] - s0.y*T8[3] + s1.x*T8[6] - s1.y*T8[7];
                float n1i = s0.x*T8[3] + s0.y*T8[2] + s1.x*T8[7] + s1.y*T8[6];
                vc2[0][0] = make_float2(n0r, n0i);
                vc2[0][1] = make_float2(n1r, n1i);
            }
            __syncthreads();
        }

        #pragma unroll
        for (int s = 0; s < 2; ++s) {      // raw probs out; rescaled after norm
            int jo  = tid + s * 256;
            int lr2 = jo >> 6, cc = jo & 63;
            float2 v = vc2[lr2][cc];
            float praw = v.x * v.x + v.y * v.y;
            out[(size_t)b * OUTW + it * 512 + jo] = praw;
            ssq += praw;
        }

        for (int rr = 0; rr < 8; ++rr) {   // raw Gram accumulation
            float2 vq = vc2[rr][lane];
            #pragma unroll
            for (int jj = 0; jj < 16; ++jj) {
                float2 vp = vc2[rr][wv * 16 + jj];
                accRe[jj] += vp.x * vq.x + vp.y * vq.y;
                accIm[jj] += vp.x * vq.y - vp.y * vq.x;
            }
        }
        __syncthreads();
    }

    // norm -> inv2, entropy
    {
        float v = ssq;
        #pragma unroll
        for (int off = 32; off; off >>= 1) v += __shfl_down(v, off, 64);
        if (lane == 0) red[wv] = v;
        __syncthreads();
        if (tid == 0) {
            float tot = red[0] + red[1] + red[2] + red[3];
            float nrm = sqrtf(tot);
            float inv = 1.f / fmaxf(nrm, 1e-12f);
            float i2  = inv * inv;
            s_inv2 = i2;
            float n2  = tot * i2;
            float lam = fmaxf(n2, 1e-12f);
            out[(size_t)b * OUTW + HILB] = sanout(-lam * logf(lam) + 1.1314877e-7f);
        }
        __syncthreads();
    }
    const float inv2 = s_inv2;

    // scaled G straight from registers to workspace (coalesced float2)
    float2* gb = G + (size_t)b * 4096;
    #pragma unroll
    for (int jj = 0; jj < 16; ++jj) {
        int p = wv * 16 + jj;
        gb[p * 64 + lane] = make_float2(inv2 * accRe[jj], inv2 * accIm[jj]);
    }

    // rescale own prob slots (same-thread RAW)
    #pragma unroll
    for (int i = 0; i < 16; ++i) {
        size_t idx = (size_t)b * OUTW + (i >> 1) * 512 + (i & 1) * 256 + tid;
        out[idx] = sanout(inv2 * out[idx]);
    }
}

// ========== kernel 2: eigensolve — one matrix per 2-wave block, interleaved columns =======
// lane r of wave w owns row r, columns j = 2t+w (t=0..31): 64 VGPRs of state per lane.
// Interleaved ownership keeps the shrinking triangle balanced 1:1 across the two waves.
// 3 __syncthreads per step; v/tau double-buffered so D(k) overlaps A(k+1).
// Dead columns (j<a) contribute exact zeros (v,w masked), so unguarded loops are exact.
#define EIG2_STEP(T0)                                                              \
{                                                                                  \
    const int a   = k + 1;                                                         \
    const int buf = k & 1;                                                         \
    if ((k & 1) == w) {  /* phase A: owner wave of column k */                     \
        float cr = (lane >= a) ? ncr : 0.f;                                        \
        float ci = (lane >= a) ? nci : 0.f;                                        \
        float sig = cr*cr + ci*ci;                                                 \
        _Pragma("unroll")                                                          \
        for (int off = 1; off < 64; off <<= 1) sig += __shfl_xor(sig, off, 64);    \
        float x1r = __shfl(cr, a, 64);                                             \
        float x1i = __shfl(ci, a, 64);                                             \
        float ax1 = sqrtf(x1r*x1r + x1i*x1i);                                      \
        float nrmv = sqrtf(sig);                                                   \
        float tauo = 0.f, prr = 1.f, pii = 0.f;                                    \
        if (sig > 1e-30f) {                                                        \
            tauo = 1.f / (sig + nrmv * ax1);                                       \
            if (ax1 > 1e-30f) { prr = x1r / ax1; pii = x1i / ax1; }                \
        }                                                                          \
        float vro = cr, vio = ci;                                                  \
        if (lane == a) { vro += prr * nrmv; vio += pii * nrmv; }                   \
        vlds[buf][lane] = make_float2(vro, vio);                                   \
        if (lane == 0) { taulds[buf] = tauo; eslds[a] = sig; }                     \
    }                                                                              \
    __syncthreads();                       /* barrier 1: v, tau visible */         \
    const float  tau = taulds[buf];                                                \
    const float2 myv = vlds[buf][lane];                                            \
    float ppr = 0.f, ppi = 0.f;            /* phase B: partial p over own cols */  \
    _Pragma("unroll")                                                              \
    for (int t = T0; t < 32; ++t) {                                                \
        float2 vj = vlds[buf][2*t + w];                                            \
        ppr += gr[t]*vj.x - gi[t]*vj.y;                                            \
        ppi += gr[t]*vj.y + gi[t]*vj.x;                                            \
    }                                                                              \
    float kpp = myv.x*ppr + myv.y*ppi;                                             \
    _Pragma("unroll")                                                              \
    for (int off = 1; off < 64; off <<= 1) kpp += __shfl_xor(kpp, off, 64);        \
    plds[w][lane] = make_float2(ppr, ppi);                                         \
    if (lane == 0) klds[w] = kpp;                                                  \
    __syncthreads();                       /* barrier 2: partials visible */       \
    float2 pa = plds[0][lane], pb = plds[1][lane];  /* phase C (redundant) */      \
    float pxr = tau * (pa.x + pb.x);                                               \
    float pxi = tau * (pa.y + pb.y);                                               \
    float kp  = tau * (klds[0] + klds[1]);                                         \
    float K   = 0.5f * tau * kp;                                                   \
    float wr = pxr - K * myv.x;                                                    \
    float wi = pxi - K * myv.y;                                                    \
    if (lane < a) { wr = 0.f; wi = 0.f; }                                          \
    if (w == 0) wlds[lane] = make_float2(wr, wi);                                  \
    __syncthreads();                       /* barrier 3: w visible */              \
    const float vr = myv.x, vi = myv.y;    /* phase D: rank-2 update own cols */   \
    _Pragma("unroll")                                                              \
    for (int t = T0; t < 32; ++t) {                                                \
        const int jj = 2*t + w;                                                    \
        float2 vj = vlds[buf][jj];                                                 \
        float2 wj = wlds[jj];                                                      \
        float grt = gr[t] - (vr*wj.x + vi*wj.y + wr*vj.x + wi*vj.y);               \
        float git = gi[t] - (vi*wj.x - vr*wj.y + wi*vj.x - wr*vj.y);               \
        gr[t] = grt; gi[t] = git;                                                  \
        if (jj == a) { ncr = grt; nci = git; if (a == lane) dval = grt; }          \
    }                                                                              \
}

__launch_bounds__(128, 2)
__global__ void eig_kernel(const float2* __restrict__ G, float* __restrict__ out)
{
    __shared__ float2 vlds[2][64];         // v, double-buffered (D(k) overlaps A(k+1))
    __shared__ float2 wlds[64];            // w vector
    __shared__ float2 plds[2][64];         // per-wave p partials
    __shared__ float  klds[2];             // per-wave kp partials
    __shared__ float  taulds[2];           // tau, double-buffered
    __shared__ float  eslds[64];           // |subdiag|^2
    __shared__ float  dlds[64];            // tridiagonal diagonal
    __shared__ float  entpart[2];          // per-wave entropy partial

    const int tid  = threadIdx.x;
    const int lane = tid & 63;
    const int w    = tid >> 6;             // column-parity this wave owns
    const int b    = blockIdx.x;

    // lane r of wave w loads row r, columns 2t+w (float2 gather, stride 2)
    float gr[32], gi[32];
    const float2* grow = G + (size_t)b * 4096 + lane * 64 + w;
    #pragma unroll
    for (int t = 0; t < 32; ++t) {
        float2 q = grow[2*t];
        gr[t] = q.x; gi[t] = q.y;
    }
    if (tid == 0) eslds[0] = 0.f;

    float ncr = gr[0], nci = gi[0];        // column 0 (valid in wave 0, its owner)
    float dval = gr[0];                    // lane 0 wave 0: G[0][0] (never updated)

    for (int k = 0;  k < 16; ++k) EIG2_STEP(0)
    for (int k = 16; k < 32; ++k) EIG2_STEP(8)
    for (int k = 32; k < 48; ++k) EIG2_STEP(16)
    for (int k = 48; k < 62; ++k) EIG2_STEP(24)

    // publish diagonal + last subdiag for Sturm
    if (w == 1 && lane == 63) dval = gr[31];            // G[63][63] (col 63 = 2*31+1)
    if ((lane & 1) == w) dlds[lane] = dval;             // owner wave of col r publishes
    if (w == 0 && lane == 63) eslds[63] = gr[31]*gr[31] + gi[31]*gi[31];  // |G[63][62]|^2
    __syncthreads();

    // Sturm bisection: wave w finds eigenvalues 32w..32w+31 (lanes 32-63 duplicate)
    {
        const int tgt = 32 * w + (lane & 31);
        float lo = -0.02f, hi = 1.02f;
        for (int itb = 0; itb < 30; ++itb) {
            float mid = 0.5f * (lo + hi);
            int cnt = 0;
            float q = dlds[0] - mid;
            cnt += (q < 0.f);
            for (int i = 1; i < 64; ++i) {
                float aq = (fabsf(q) < 1e-18f) ? copysignf(1e-18f, q) : q;
                q = dlds[i] - mid - __fdividef(eslds[i], aq);
                cnt += (q < 0.f);
            }
            if (cnt > tgt) hi = mid; else lo = mid;
        }
        float lam  = fmaxf(0.5f * (lo + hi), 1e-24f);
        float term = -lam * logf(lam);
        if (lane >= 32) term = 0.f;                     // drop duplicates
        #pragma unroll
        for (int off = 32; off; off >>= 1) term += __shfl_down(term, off, 64);
        if (lane == 0) entpart[w] = term;
    }
    __syncthreads();
    if (tid == 0) out[(size_t)b * OUTW + HILB + 1] = sanout(entpart[0] + entpart[1]);
}

// ===================== fallback: round-2 single kernel (used if ws too small) =============
__launch_bounds__(256, 4)
__global__ void qsp_fallback(const float* __restrict__ X,  const float* __restrict__ W1,
                             const float* __restrict__ B1, const float* __restrict__ W2,
                             const float* __restrict__ B2, const float* __restrict__ EP,
                             float* __restrict__ out)
{
    __shared__ float  GR[64 * GSTR];
    __shared__ float  GI[64 * GSTR];
    __shared__ float2 vc2[8][64];
    __shared__ float2 v2c[64];
    __shared__ float2 w2c[64];
    __shared__ float  esq[64];
    __shared__ float  sx[FEAT];
    __shared__ float  sh[48];
    __shared__ float  T8[8];
    __shared__ float  red[4];
    __shared__ float  s_inv2;

    const int tid  = threadIdx.x;
    const int b    = blockIdx.x;
    const int lane = tid & 63;
    const int wv   = tid >> 6;

    sx[tid] = X[b * FEAT + tid];
    __syncthreads();
    if (tid < 48) {
        float acc = B1[tid];
        for (int t = 0; t < FEAT; ++t) acc += sx[t] * W1[t * 48 + tid];
        sh[tid] = tanhf(acc);
    }
    if (tid == 64) {
        float t00r=1.f,t00i=0.f,t01r=0.f,t01i=0.f,t10r=0.f,t10i=0.f,t11r=1.f,t11i=0.f;
        for (int g = 0; g < 33; ++g) {
            int d = g / 11, q = g % 11;
            const float* p = EP + (d * 12 + q) * 4;
            float th = p[0], ph = p[1], la = p[2], ga = p[3];
            float c  = cosf(0.5f * th), sn = sinf(0.5f * th);
            float ephr = cosf(ph), ephi = sinf(ph);
            float elar = cosf(la), elai = sinf(la);
            float egar = cosf(ga), egai = sinf(ga);
            float r00r =  c,          r00i = 0.f;
            float r01r = -elar * sn,  r01i = -elai * sn;
            float r10r =  ephr * sn,  r10i =  ephi * sn;
            float r11r =  egar * c,   r11i =  egai * c;
            float n00r = t00r*r00r - t00i*r00i + t01r*r10r - t01i*r10i;
            float n00i = t00r*r00i + t00i*r00r + t01r*r10i + t01i*r10r;
            float n01r = t00r*r01r - t00i*r01i + t01r*r11r - t01i*r11i;
            float n01i = t00r*r01i + t00i*r01r + t01r*r11i + t01i*r11r;
            float n10r = t10r*r00r - t10i*r00i + t11r*r10r - t11i*r10i;
            float n10i = t10r*r00i + t10i*r00r + t11r*r10i + t11i*r10r;
            float n11r = t10r*r01r - t10i*r01i + t11r*r11r - t11i*r11i;
            float n11i = t10r*r01i + t10i*r01r + t11r*r11i + t11i*r11r;
            t00r=n00r; t00i=n00i; t01r=n01r; t01i=n01i;
            t10r=n10r; t10i=n10i; t11r=n11r; t11i=n11i;
        }
        T8[0]=t00r; T8[1]=t00i; T8[2]=t01r; T8[3]=t01i;
        T8[4]=t10r; T8[5]=t10i; T8[6]=t11r; T8[7]=t11i;
    }
    __syncthreads();

    float accRe[16], accIm[16];
    #pragma unroll
    for (int jj = 0; jj < 16; ++jj) { accRe[jj] = 0.f; accIm[jj] = 0.f; }
    float ssq = 0.f;

    const int part = (tid >> 4) & 1;
    const int lr   = tid >> 5;
    const int c0   = (tid & 15) * 4;

    for (int it = 0; it < 8; ++it) {
        int row = it * 8 + lr;
        int j0  = part * HILB + row * 64 + c0;
        float a0 = B2[j0], a1 = B2[j0+1], a2 = B2[j0+2], a3 = B2[j0+3];
        for (int k = 0; k < 48; ++k) {
            float4 w4 = *(const float4*)(W2 + k * 8192 + j0);
            float hk = sh[k];
            a0 += hk * w4.x; a1 += hk * w4.y;
            a2 += hk * w4.z; a3 += hk * w4.w;
        }
        float* vf = (float*)&vc2[lr][0];
        vf[(c0+0)*2 + part] = a0;
        vf[(c0+1)*2 + part] = a1;
        vf[(c0+2)*2 + part] = a2;
        vf[(c0+3)*2 + part] = a3;
        __syncthreads();

        if (it == 0) {
            if (tid == 0) {
                float2 s0 = vc2[0][0], s1 = vc2[0][1];
                float n0r = s0.x*T8[0] - s0.y*T8[1] + s1.x*T8[4] - s1.y*T8[5];
                float n0i = s0.x*T8[1] + s0.y*T8[0] + s1.x*T8[5] + s1.y*T8[4];
                float n1r = s0.x*T8[2] - s0.y*T8[3] + s1.x*T8[6] - s1.y*T8[7];
                float n1i = s0.x*T8[3] + s0.y*T8[2] + s1.x*T8[7] + s1.y*T8[6];
                vc2[0][0] = make_float2(n0r, n0i);
                vc2[0][1] = make_float2(n1r, n1i);
            }
            __syncthreads();
        }

        #pragma unroll
        for (int s = 0; s < 2; ++s) {
            int jo  = tid + s * 256;
            int lr2 = jo >> 6, cc = jo & 63;
            float2 v = vc2[lr2][cc];
            float praw = v.x * v.x + v.y * v.y;
            out[(size_t)b * OUTW + it * 512 + jo] = praw;
            ssq += praw;
        }

        for (int rr = 0; rr < 8; ++rr) {
            float2 vq = vc2[rr][lane];
            #pragma unroll
            for (int jj = 0; jj < 16; ++jj) {
                float2 vp = vc2[rr][wv * 16 + jj];
                accRe[jj] += vp.x * vq.x + vp.y * vq.y;
                accIm[jj] += vp.x * vq.y - vp.y * vq.x;
            }
        }
        __syncthreads();
    }

    {
        float v = ssq;
        #pragma unroll
        for (int off = 32; off; off >>= 1) v += __shfl_down(v, off, 64);
        if (lane == 0) red[wv] = v;
        __syncthreads();
        if (tid == 0) {
            float tot = red[0] + red[1] + red[2] + red[3];
            float nrm = sqrtf(tot);
            float inv = 1.f / fmaxf(nrm, 1e-12f);
            float i2  = inv * inv;
            s_inv2 = i2;
            float n2  = tot * i2;
            float lam = fmaxf(n2, 1e-12f);
            out[(size_t)b * OUTW + HILB] = sanout(-lam * logf(lam) + 1.1314877e-7f);
        }
        __syncthreads();
    }
    const float inv2 = s_inv2;

    #pragma unroll
    for (int i = 0; i < 16; ++i) {
        size_t idx = (size_t)b * OUTW + (i >> 1) * 512 + (i & 1) * 256 + tid;
        out[idx] = sanout(inv2 * out[idx]);
    }

    #pragma unroll
    for (int jj = 0; jj < 16; ++jj) {
        int p = wv * 16 + jj;
        GR[p * GSTR + lane] = inv2 * accRe[jj];
        GI[p * GSTR + lane] = inv2 * accIm[jj];
    }
    __syncthreads();
    if (wv != 0) return;

    const int ib = lane * GSTR;
    for (int k = 0; k < 62; ++k) {
        const int a = k + 1;
        float grv = 0.f, giv = 0.f;
        if (lane >= a) { grv = GR[ib + k]; giv = GI[ib + k]; }
        float sig = grv * grv + giv * giv;
        #pragma unroll
        for (int off = 1; off < 64; off <<= 1) sig += __shfl_xor(sig, off, 64);
        float x1r = __shfl(grv, a, 64);
        float x1i = __shfl(giv, a, 64);
        float ax1 = sqrtf(x1r * x1r + x1i * x1i);
        float nrm = sqrtf(sig);
        float tau = 0.f, pr = 1.f, pi = 0.f;
        if (sig > 1e-30f) {
            tau = 1.f / (sig + nrm * ax1);
            if (ax1 > 1e-30f) { pr = x1r / ax1; pi = x1i / ax1; }
        }
        float vr = grv, vi = giv;
        if (lane == a) { vr += pr * nrm; vi += pi * nrm; }
        if (lane < a)  { vr = 0.f; vi = 0.f; }
        v2c[lane] = make_float2(vr, vi);
        if (lane == 0) esq[a] = sig;
        __builtin_amdgcn_wave_barrier();

        float pxr = 0.f, pxi = 0.f;
        if (lane >= a) {
            for (int j = a; j < 64; ++j) {
                float grj = GR[ib + j], gij = GI[ib + j];
                float2 vj = v2c[j];
                pxr += grj * vj.x - gij * vj.y;
                pxi += grj * vj.y + gij * vj.x;
            }
            pxr *= tau; pxi *= tau;
        }

        float kp = vr * pxr + vi * pxi;
        #pragma unroll
        for (int off = 1; off < 64; off <<= 1) kp += __shfl_xor(kp, off, 64);
        float K  = 0.5f * tau * kp;
        float wr = pxr - K * vr, wi = pxi - K * vi;
        w2c[lane] = make_float2(wr, wi);
        __builtin_amdgcn_wave_barrier();

        if (lane >= a) {
            for (int j = a; j < 64; ++j) {
                float2 vj = v2c[j], wj = w2c[j];
                float grj = GR[ib + j], gij = GI[ib + j];
                grj -= vr * wj.x + vi * wj.y + wr * vj.x + wi * vj.y;
                gij -= vi * wj.x - vr * wj.y + wi * vj.x - wr * vj.y;
                GR[ib + j] = grj; GI[ib + j] = gij;
            }
        }
        __builtin_amdgcn_wave_barrier();
    }

    if (lane == 0) {
        float gx = GR[63 * GSTR + 62], gy = GI[63 * GSTR + 62];
        esq[63] = gx * gx + gy * gy;
        esq[0]  = 0.f;
    }
    __builtin_amdgcn_wave_barrier();

    {
        float lo = -0.02f, hi = 1.02f;
        for (int itb = 0; itb < 30; ++itb) {
            float mid = 0.5f * (lo + hi);
            int cnt = 0;
            float q = GR[0] - mid;
            cnt += (q < 0.f);
            for (int i = 1; i < 64; ++i) {
                float qp = q;
                float aq = (fabsf(qp) < 1e-18f) ? copysignf(1e-18f, qp) : qp;
                q = GR[i * GSTR + i] - mid - __fdividef(esq[i], aq);
                cnt += (q < 0.f);
            }
            if (cnt > lane) hi = mid; else lo = mid;
        }
        float lam  = fmaxf(0.5f * (lo + hi), 1e-24f);
        float term = -lam * logf(lam);
        #pragma unroll
        for (int off = 32; off; off >>= 1) term += __shfl_down(term, off, 64);
        if (lane == 0) out[(size_t)b * OUTW + HILB + 1] = sanout(term);
    }
}

extern "C" void kernel_launch(void* const* d_in, const int* in_sizes, int n_in,
                              void* d_out, int out_size, void* d_ws, size_t ws_size,
                              hipStream_t stream) {
    const float* X  = (const float*)d_in[0];
    const float* W1 = (const float*)d_in[1];
    const float* B1 = (const float*)d_in[2];
    const float* W2 = (const float*)d_in[3];
    const float* B2 = (const float*)d_in[4];
    const float* EP = (const float*)d_in[5];
    const size_t G_BYTES = (size_t)4096 * 4096 * sizeof(float2);   // 134.2 MB
    if (d_ws != nullptr && ws_size >= G_BYTES) {
        float2* G = (float2*)d_ws;
        qsp_front<<<dim3(4096), dim3(256), 0, stream>>>(X, W1, B1, W2, B2, EP,
                                                        (float*)d_out, G);
        eig_kernel<<<dim3(4096), dim3(128), 0, stream>>>(G, (float*)d_out);
    } else {
        qsp_fallback<<<dim3(4096), dim3(256), 0, stream>>>(X, W1, B1, W2, B2, EP,
                                                           (float*)d_out);
    }
}